// Round 6
// baseline (1131.285 us; speedup 1.0000x reference)
//
#include <hip/hip_runtime.h>
#include <math.h>

#define BN_EPS 1e-5f
#define N_NODES 50000
#define E_EDGES 600000

// ------------------------------------------------------------ static scratch
// (BSS device globals: avoids any assumption about ws_size; ~320 MB total)
__device__ float g_bufA[(size_t)N_NODES * 512];   // xl1 | xl2+xr2
__device__ float g_bufB[(size_t)N_NODES * 512];   // xr1 | z
__device__ float g_bufC[(size_t)N_NODES * 512];   // h1
__device__ int   g_rowptr[N_NODES + 1];
__device__ int   g_bsum[256];
__device__ int   g_cursor[N_NODES];
__device__ int   g_counts[N_NODES];
__device__ int   g_csrc[E_EDGES + N_NODES];

// ---------------------------------------------------------------- CSR build

__global__ void k_init_counts(int* __restrict__ counts, int n) {
    int i = blockIdx.x * blockDim.x + threadIdx.x;
    if (i < n) counts[i] = 1;   // self-loop contributes 1 incoming edge
}

__global__ void k_hist(const int* __restrict__ ei, int E, int* __restrict__ counts) {
    int e = blockIdx.x * blockDim.x + threadIdx.x;
    if (e < E) atomicAdd(&counts[ei[E + e]], 1);   // dst = ei[1][e]
}

// per-block inclusive scan of counts -> rowptr[i+1]; block sums -> bsum
__global__ void k_scan1(const int* __restrict__ counts, int n,
                        int* __restrict__ rp, int* __restrict__ bsum) {
    __shared__ int sd[256];
    int t = threadIdx.x;
    int g = blockIdx.x * 256 + t;
    int v = (g < n) ? counts[g] : 0;
    sd[t] = v;
    __syncthreads();
    for (int o = 1; o < 256; o <<= 1) {
        int u = (t >= o) ? sd[t - o] : 0;
        __syncthreads();
        sd[t] += u;
        __syncthreads();
    }
    if (g < n) rp[g + 1] = sd[t];
    if (t == 255) bsum[blockIdx.x] = sd[255];
}

// exclusive scan of block sums (nb <= 256), single block
__global__ void k_scan2(int* __restrict__ bsum, int nb) {
    __shared__ int sd[256];
    int t = threadIdx.x;
    int v = (t < nb) ? bsum[t] : 0;
    sd[t] = v;
    __syncthreads();
    for (int o = 1; o < 256; o <<= 1) {
        int u = (t >= o) ? sd[t - o] : 0;
        __syncthreads();
        sd[t] += u;
        __syncthreads();
    }
    if (t < nb) bsum[t] = sd[t] - v;
}

__global__ void k_scan3(int* __restrict__ rp, const int* __restrict__ bsum, int n) {
    int g = blockIdx.x * blockDim.x + threadIdx.x;
    if (g < n) rp[g + 1] += bsum[g >> 8];
    if (g == 0) rp[0] = 0;
}

// place self-loop first in each segment, set cursor past it
__global__ void k_fill(const int* __restrict__ rp, int* __restrict__ cursor,
                       int* __restrict__ csrc, int n) {
    int i = blockIdx.x * blockDim.x + threadIdx.x;
    if (i < n) {
        int p = rp[i];
        csrc[p] = i;
        cursor[i] = p + 1;
    }
}

__global__ void k_scatter(const int* __restrict__ ei, int E,
                          int* __restrict__ cursor, int* __restrict__ csrc) {
    int e = blockIdx.x * blockDim.x + threadIdx.x;
    if (e < E) {
        int d = ei[E + e];
        int p = atomicAdd(&cursor[d], 1);
        csrc[p] = ei[e];   // src = ei[0][e]
    }
}

// ---------------------------------------------------------------- f32 GEMM
// C[M,Nc] = A[M,K] @ W[K,Nc] + bias[Nc].  64x64 tile, BK=32, 256 thr, 4x4/thr.
__global__ void k_gemm_bias(const float* __restrict__ A, const float* __restrict__ W,
                            const float* __restrict__ bias, float* __restrict__ C,
                            int M, int Nc, int K) {
    __shared__ float sA[32][68];
    __shared__ float sB[32][68];
    int tid = threadIdx.x;
    int tx = tid & 15;     // -> M direction
    int ty = tid >> 4;     // -> N direction
    int m0 = blockIdx.y * 64;
    int n0 = blockIdx.x * 64;
    float acc[4][4] = {};
    for (int k0 = 0; k0 < K; k0 += 32) {
        #pragma unroll
        for (int i = 0; i < 2; i++) {
            int idx = tid + i * 256;        // 0..511
            int r = idx >> 3;               // 0..63
            int c4 = (idx & 7) * 4;         // 0..28
            int gr = m0 + r;
            float4 v = make_float4(0.f, 0.f, 0.f, 0.f);
            if (gr < M) v = *(const float4*)(A + (size_t)gr * K + k0 + c4);
            sA[c4 + 0][r] = v.x; sA[c4 + 1][r] = v.y;
            sA[c4 + 2][r] = v.z; sA[c4 + 3][r] = v.w;
        }
        #pragma unroll
        for (int i = 0; i < 2; i++) {
            int idx = tid + i * 256;
            int r = idx >> 4;               // 0..31
            int c4 = (idx & 15) * 4;        // 0..60
            float4 v = *(const float4*)(W + (size_t)(k0 + r) * Nc + n0 + c4);
            *(float4*)&sB[r][c4] = v;
        }
        __syncthreads();
        #pragma unroll
        for (int k = 0; k < 32; k++) {
            float a[4], b[4];
            *(float4*)a = *(const float4*)&sA[k][tx * 4];
            *(float4*)b = *(const float4*)&sB[k][ty * 4];
            #pragma unroll
            for (int i = 0; i < 4; i++)
                #pragma unroll
                for (int j = 0; j < 4; j++)
                    acc[i][j] += a[i] * b[j];
        }
        __syncthreads();
    }
    #pragma unroll
    for (int i = 0; i < 4; i++) {
        int gr = m0 + tx * 4 + i;
        if (gr < M) {
            #pragma unroll
            for (int j = 0; j < 4; j++) {
                int gc = n0 + ty * 4 + j;
                C[(size_t)gr * Nc + gc] = acc[i][j] + bias[gc];
            }
        }
    }
}

// ------------------------------------------------- GATv2 flash aggregation
// one wave per dst node; online softmax over incoming edges; fused bias+BN+relu
template <int H>
__global__ void k_gat_agg(const float* __restrict__ xl, const float* __restrict__ xr,
                          const float* __restrict__ att,
                          const int* __restrict__ rp, const int* __restrict__ csrc,
                          const float* __restrict__ bias,
                          const float* __restrict__ bng, const float* __restrict__ bnb,
                          const float* __restrict__ bnm, const float* __restrict__ bnv,
                          float* __restrict__ out, int n) {
    const int D = H * 128;
    int wid = (blockIdx.x * blockDim.x + threadIdx.x) >> 6;
    int lane = threadIdx.x & 63;
    if (wid >= n) return;
    const int i = wid;

    float xrv[H][2], attv[H][2];
    #pragma unroll
    for (int h = 0; h < H; h++) {
        float2 t = *(const float2*)(xr + (size_t)i * D + h * 128 + lane * 2);
        xrv[h][0] = t.x; xrv[h][1] = t.y;
        float2 a = *(const float2*)(att + h * 128 + lane * 2);
        attv[h][0] = a.x; attv[h][1] = a.y;
    }
    float m[H], dnm[H], acc[H][2];
    #pragma unroll
    for (int h = 0; h < H; h++) {
        m[h] = -INFINITY; dnm[h] = 0.f; acc[h][0] = 0.f; acc[h][1] = 0.f;
    }

    int e0 = rp[i], e1 = rp[i + 1];
    for (int e = e0; e < e1; e++) {
        int j = csrc[e];
        float xlv[H][2], part[H];
        #pragma unroll
        for (int h = 0; h < H; h++) {
            float2 t = *(const float2*)(xl + (size_t)j * D + h * 128 + lane * 2);
            xlv[h][0] = t.x; xlv[h][1] = t.y;
            float v0 = t.x + xrv[h][0];
            float v1 = t.y + xrv[h][1];
            v0 = fmaxf(v0, 0.2f * v0);
            v1 = fmaxf(v1, 0.2f * v1);
            part[h] = attv[h][0] * v0 + attv[h][1] * v1;
        }
        #pragma unroll
        for (int h = 0; h < H; h++) {
            float s = part[h];
            #pragma unroll
            for (int o = 32; o > 0; o >>= 1) s += __shfl_xor(s, o, 64);
            float mn = fmaxf(m[h], s);
            float scale = __expf(m[h] - mn);
            float p = __expf(s - mn);
            dnm[h] = dnm[h] * scale + p;
            acc[h][0] = acc[h][0] * scale + p * xlv[h][0];
            acc[h][1] = acc[h][1] * scale + p * xlv[h][1];
            m[h] = mn;
        }
    }
    #pragma unroll
    for (int h = 0; h < H; h++) {
        float inv = 1.f / dnm[h];
        #pragma unroll
        for (int q = 0; q < 2; q++) {
            int ch = h * 128 + lane * 2 + q;
            float o = acc[h][q] * inv + bias[ch];
            float vv = (o - bnm[ch]) * rsqrtf(bnv[ch] + BN_EPS) * bng[ch] + bnb[ch];
            out[(size_t)i * D + ch] = fmaxf(vv, 0.f);
        }
    }
}

// ---------------------------------------------------------- prediction head
__global__ void k_pred(const float* __restrict__ z, const int* __restrict__ pe,
                       const float* __restrict__ pr, const float* __restrict__ pert,
                       const float* __restrict__ Wp, const float* __restrict__ bp,
                       float* __restrict__ out, int P) {
    int wid = (blockIdx.x * blockDim.x + threadIdx.x) >> 6;
    int lane = threadIdx.x & 63;
    if (wid >= P) return;
    int s = pe[wid], d = pe[P + wid];
    float4 zs = *(const float4*)(z + (size_t)s * 256 + lane * 4);
    float4 zd = *(const float4*)(z + (size_t)d * 256 + lane * 4);
    float a0 = 0.f, a1 = 0.f;
    const float* zsp = (const float*)&zs;
    const float* zdp = (const float*)&zd;
    #pragma unroll
    for (int q = 0; q < 4; q++) {
        int f1 = lane * 4 + q;
        int f2 = 256 + lane * 4 + q;
        a0 += zsp[q] * Wp[f1 * 2 + 0] + zdp[q] * Wp[f2 * 2 + 0];
        a1 += zsp[q] * Wp[f1 * 2 + 1] + zdp[q] * Wp[f2 * 2 + 1];
    }
    #pragma unroll
    for (int o = 32; o > 0; o >>= 1) {
        a0 += __shfl_xor(a0, o, 64);
        a1 += __shfl_xor(a1, o, 64);
    }
    if (lane == 0) {
        float prs = pr[s], prd = pr[d], pp = pert[s] * pert[d];
        a0 += prs * Wp[512 * 2 + 0] + prd * Wp[513 * 2 + 0] + pp * Wp[514 * 2 + 0] + bp[0];
        a1 += prs * Wp[512 * 2 + 1] + prd * Wp[513 * 2 + 1] + pp * Wp[514 * 2 + 1] + bp[1];
        *(float2*)(out + (size_t)wid * 2) = make_float2(a0, a1);
    }
}

// ---------------------------------------------------------------------------

extern "C" void kernel_launch(void* const* d_in, const int* in_sizes, int n_in,
                              void* d_out, int out_size, void* d_ws, size_t ws_size,
                              hipStream_t stream) {
    const float* x    = (const float*)d_in[0];
    const int*   ei   = (const int*)d_in[1];
    const int*   pe   = (const int*)d_in[2];
    const float* pert = (const float*)d_in[3];
    const float* pr   = (const float*)d_in[4];
    const float* Wl1  = (const float*)d_in[5];
    const float* bl1  = (const float*)d_in[6];
    const float* Wr1  = (const float*)d_in[7];
    const float* br1  = (const float*)d_in[8];
    const float* att1 = (const float*)d_in[9];
    const float* bias1= (const float*)d_in[10];
    const float* bn1g = (const float*)d_in[11];
    const float* bn1b = (const float*)d_in[12];
    const float* bn1m = (const float*)d_in[13];
    const float* bn1v = (const float*)d_in[14];
    const float* Wl2  = (const float*)d_in[15];
    const float* bl2  = (const float*)d_in[16];
    const float* Wr2  = (const float*)d_in[17];
    const float* br2  = (const float*)d_in[18];
    const float* att2 = (const float*)d_in[19];
    const float* bias2= (const float*)d_in[20];
    const float* bn2g = (const float*)d_in[21];
    const float* bn2b = (const float*)d_in[22];
    const float* bn2m = (const float*)d_in[23];
    const float* bn2v = (const float*)d_in[24];
    const float* Wp   = (const float*)d_in[25];
    const float* bp   = (const float*)d_in[26];

    const int n  = in_sizes[3];          // 50000 (pert has N elements)
    const int E  = in_sizes[1] / 2;      // 600000
    const int P  = in_sizes[2] / 2;      // 200000
    const int IN = in_sizes[0] / n;      // 128
    const int D1 = 512, D2 = 256;

    // resolve static scratch pointers once (sync runtime query; not a stream op)
    static float* bufA = nullptr;
    static float* bufB = nullptr;
    static float* bufC = nullptr;
    static int *rowptr = nullptr, *bsum = nullptr, *cursor = nullptr,
               *counts = nullptr, *csrc = nullptr;
    if (!bufA) {
        hipGetSymbolAddress((void**)&bufA,   HIP_SYMBOL(g_bufA));
        hipGetSymbolAddress((void**)&bufB,   HIP_SYMBOL(g_bufB));
        hipGetSymbolAddress((void**)&bufC,   HIP_SYMBOL(g_bufC));
        hipGetSymbolAddress((void**)&rowptr, HIP_SYMBOL(g_rowptr));
        hipGetSymbolAddress((void**)&bsum,   HIP_SYMBOL(g_bsum));
        hipGetSymbolAddress((void**)&cursor, HIP_SYMBOL(g_cursor));
        hipGetSymbolAddress((void**)&counts, HIP_SYMBOL(g_counts));
        hipGetSymbolAddress((void**)&csrc,   HIP_SYMBOL(g_csrc));
    }

    float* xl1 = bufA;
    float* xr1 = bufB;
    float* h1  = bufC;
    float* xl2 = bufA;                        // reuse
    float* xr2 = bufA + (size_t)n * D2;       // second half of bufA
    float* z   = bufB;                        // reuse

    const int nb = (n + 255) / 256;   // 196 scan blocks (<=256 required)

    // ---- CSR build
    k_init_counts<<<nb, 256, 0, stream>>>(counts, n);
    k_hist<<<(E + 255) / 256, 256, 0, stream>>>(ei, E, counts);
    k_scan1<<<nb, 256, 0, stream>>>(counts, n, rowptr, bsum);
    k_scan2<<<1, 256, 0, stream>>>(bsum, nb);
    k_scan3<<<nb, 256, 0, stream>>>(rowptr, bsum, n);
    k_fill<<<nb, 256, 0, stream>>>(rowptr, cursor, csrc, n);
    k_scatter<<<(E + 255) / 256, 256, 0, stream>>>(ei, E, cursor, csrc);

    // ---- layer 1
    {
        dim3 grid(D1 / 64, (n + 63) / 64);
        k_gemm_bias<<<grid, 256, 0, stream>>>(x, Wl1, bl1, xl1, n, D1, IN);
        k_gemm_bias<<<grid, 256, 0, stream>>>(x, Wr1, br1, xr1, n, D1, IN);
    }
    k_gat_agg<4><<<(n + 3) / 4, 256, 0, stream>>>(xl1, xr1, att1, rowptr, csrc,
                                                  bias1, bn1g, bn1b, bn1m, bn1v, h1, n);
    // ---- layer 2
    {
        dim3 grid(D2 / 64, (n + 63) / 64);
        k_gemm_bias<<<grid, 256, 0, stream>>>(h1, Wl2, bl2, xl2, n, D2, D1);
        k_gemm_bias<<<grid, 256, 0, stream>>>(h1, Wr2, br2, xr2, n, D2, D1);
    }
    k_gat_agg<2><<<(n + 3) / 4, 256, 0, stream>>>(xl2, xr2, att2, rowptr, csrc,
                                                  bias2, bn2g, bn2b, bn2m, bn2v, z, n);
    // ---- prediction head
    k_pred<<<(P + 3) / 4, 256, 0, stream>>>(z, pe, pr, pert, Wp, bp,
                                            (float*)d_out, P);
}

// Round 7
// 803.741 us; speedup vs baseline: 1.4075x; 1.4075x over previous
//
#include <hip/hip_runtime.h>
#include <math.h>

#define BN_EPS 1e-5f
#define N_NODES 50000
#define E_EDGES 600000

typedef __attribute__((ext_vector_type(8))) short bf16x8;
typedef __attribute__((ext_vector_type(4))) float f32x4;

__device__ __forceinline__ short f2bf(float f) {
    unsigned u = __float_as_uint(f);
    u += 0x7fffu + ((u >> 16) & 1u);      // RNE to bf16
    return (short)(u >> 16);
}
__device__ __forceinline__ float bf2f(short s) {
    return __uint_as_float(((unsigned)(unsigned short)s) << 16);
}

// ------------------------------------------------------------ static scratch
__device__ float g_bufA[(size_t)N_NODES * 512];   // xl1 | xl2(lo)+xr2(hi)
__device__ float g_bufB[(size_t)N_NODES * 512];   // xr1 | z
__device__ short g_h1b[(size_t)N_NODES * 512];    // h1 (bf16)
__device__ short g_xb[(size_t)N_NODES * 128];     // x (bf16)
__device__ short g_wt[393216];                    // Wl1t|Wr1t|Wl2t|Wr2t (bf16)
__device__ int   g_rowptr[N_NODES + 1];
__device__ int   g_bsum[256];
__device__ int   g_cursor[N_NODES];
__device__ int   g_counts[N_NODES];
__device__ int   g_csrc[E_EDGES + N_NODES];

// ---------------------------------------------------------------- CSR build

__global__ void k_init_counts(int* __restrict__ counts, int n) {
    int i = blockIdx.x * blockDim.x + threadIdx.x;
    if (i < n) counts[i] = 1;
}

__global__ void k_hist(const int* __restrict__ ei, int E, int* __restrict__ counts) {
    int e = blockIdx.x * blockDim.x + threadIdx.x;
    if (e < E) atomicAdd(&counts[ei[E + e]], 1);
}

__global__ void k_scan1(const int* __restrict__ counts, int n,
                        int* __restrict__ rp, int* __restrict__ bsum) {
    __shared__ int sd[256];
    int t = threadIdx.x;
    int g = blockIdx.x * 256 + t;
    int v = (g < n) ? counts[g] : 0;
    sd[t] = v;
    __syncthreads();
    for (int o = 1; o < 256; o <<= 1) {
        int u = (t >= o) ? sd[t - o] : 0;
        __syncthreads();
        sd[t] += u;
        __syncthreads();
    }
    if (g < n) rp[g + 1] = sd[t];
    if (t == 255) bsum[blockIdx.x] = sd[255];
}

__global__ void k_scan2(int* __restrict__ bsum, int nb) {
    __shared__ int sd[256];
    int t = threadIdx.x;
    int v = (t < nb) ? bsum[t] : 0;
    sd[t] = v;
    __syncthreads();
    for (int o = 1; o < 256; o <<= 1) {
        int u = (t >= o) ? sd[t - o] : 0;
        __syncthreads();
        sd[t] += u;
        __syncthreads();
    }
    if (t < nb) bsum[t] = sd[t] - v;
}

__global__ void k_scan3(int* __restrict__ rp, const int* __restrict__ bsum, int n) {
    int g = blockIdx.x * blockDim.x + threadIdx.x;
    if (g < n) rp[g + 1] += bsum[g >> 8];
    if (g == 0) rp[0] = 0;
}

__global__ void k_fill(const int* __restrict__ rp, int* __restrict__ cursor,
                       int* __restrict__ csrc, int n) {
    int i = blockIdx.x * blockDim.x + threadIdx.x;
    if (i < n) {
        int p = rp[i];
        csrc[p] = i;
        cursor[i] = p + 1;
    }
}

__global__ void k_scatter(const int* __restrict__ ei, int E,
                          int* __restrict__ cursor, int* __restrict__ csrc) {
    int e = blockIdx.x * blockDim.x + threadIdx.x;
    if (e < E) {
        int d = ei[E + e];
        int p = atomicAdd(&cursor[d], 1);
        csrc[p] = ei[e];
    }
}

// -------------------------------------------------------------- conversions

__global__ void k_f32_to_bf16_v4(const float* __restrict__ in, short* __restrict__ out,
                                 int n4) {
    int i = blockIdx.x * blockDim.x + threadIdx.x;
    if (i < n4) {
        float4 v = ((const float4*)in)[i];
        short4 o;
        o.x = f2bf(v.x); o.y = f2bf(v.y); o.z = f2bf(v.z); o.w = f2bf(v.w);
        ((short4*)out)[i] = o;
    }
}

// W [K,N] f32 -> Wt [N,K] bf16.  K,N multiples of 32.  block (32,8)
__global__ void k_transpose_w(const float* __restrict__ W, short* __restrict__ Wt,
                              int K, int N) {
    __shared__ float s[32][33];
    int n0 = blockIdx.x * 32, k0 = blockIdx.y * 32;
    int tx = threadIdx.x, ty = threadIdx.y;
    #pragma unroll
    for (int q = 0; q < 4; q++)
        s[ty * 4 + q][tx] = W[(size_t)(k0 + ty * 4 + q) * N + n0 + tx];
    __syncthreads();
    #pragma unroll
    for (int q = 0; q < 4; q++)
        Wt[(size_t)(n0 + ty * 4 + q) * K + k0 + tx] = f2bf(s[tx][ty * 4 + q]);
}

// ------------------------------------------------------------ bf16 MFMA GEMM
// C[M,N] = A[M,K](bf16) @ Bt[N,K](bf16)^T + bias.  128x128 tile, BK=64,
// 4 waves (2x2), each wave 64x64 = 4x4 frags of 16x16x32. Padded LDS (72)
// gives conflict-free b128 access (8 lanes/bank-quad uniform).
__global__ __launch_bounds__(256) void k_gemm_mfma(
    const short* __restrict__ A, const short* __restrict__ Bt,
    const float* __restrict__ bias, float* __restrict__ C,
    int M, int N, int K)
{
    __shared__ short sA[128][72];
    __shared__ short sB[128][72];
    int tid = threadIdx.x;
    int wid = tid >> 6, lane = tid & 63;
    int m0 = blockIdx.y * 128, n0 = blockIdx.x * 128;
    int wr = (wid >> 1) * 64;
    int wc = (wid & 1) * 64;
    f32x4 acc[4][4] = {};

    for (int k0 = 0; k0 < K; k0 += 64) {
        #pragma unroll
        for (int i = 0; i < 4; i++) {
            int c = tid + i * 256;          // 0..1023
            int r = c >> 3;                 // 0..127
            int col = (c & 7) * 8;          // 0..56
            bf16x8 v = {};
            int gr = m0 + r;
            if (gr < M) v = *(const bf16x8*)(A + (size_t)gr * K + k0 + col);
            *(bf16x8*)&sA[r][col] = v;
        }
        #pragma unroll
        for (int i = 0; i < 4; i++) {
            int c = tid + i * 256;
            int r = c >> 3;
            int col = (c & 7) * 8;
            bf16x8 v = *(const bf16x8*)(Bt + (size_t)(n0 + r) * K + k0 + col);
            *(bf16x8*)&sB[r][col] = v;
        }
        __syncthreads();
        #pragma unroll
        for (int kk = 0; kk < 2; kk++) {
            bf16x8 af[4], bfr[4];
            #pragma unroll
            for (int i = 0; i < 4; i++)
                af[i] = *(bf16x8*)&sA[wr + i * 16 + (lane & 15)][kk * 32 + (lane >> 4) * 8];
            #pragma unroll
            for (int j = 0; j < 4; j++)
                bfr[j] = *(bf16x8*)&sB[wc + j * 16 + (lane & 15)][kk * 32 + (lane >> 4) * 8];
            #pragma unroll
            for (int i = 0; i < 4; i++)
                #pragma unroll
                for (int j = 0; j < 4; j++)
                    acc[i][j] = __builtin_amdgcn_mfma_f32_16x16x32_bf16(
                        af[i], bfr[j], acc[i][j], 0, 0, 0);
        }
        __syncthreads();
    }
    // epilogue: C/D layout col=lane&15, row=(lane>>4)*4+q  [verified m89/m91]
    #pragma unroll
    for (int i = 0; i < 4; i++) {
        #pragma unroll
        for (int j = 0; j < 4; j++) {
            int colg = n0 + wc + j * 16 + (lane & 15);
            float b = bias[colg];
            #pragma unroll
            for (int q = 0; q < 4; q++) {
                int rowg = m0 + wr + i * 16 + (lane >> 4) * 4 + q;
                if (rowg < M) C[(size_t)rowg * N + colg] = acc[i][j][q] + b;
            }
        }
    }
}

// ------------------------------------------------- GATv2 flash aggregation
template <int H, typename OT>
__global__ void k_gat_agg(const float* __restrict__ xl, const float* __restrict__ xr,
                          const float* __restrict__ att,
                          const int* __restrict__ rp, const int* __restrict__ csrc,
                          const float* __restrict__ bias,
                          const float* __restrict__ bng, const float* __restrict__ bnb,
                          const float* __restrict__ bnm, const float* __restrict__ bnv,
                          OT* __restrict__ out, int n) {
    const int D = H * 128;
    int wid = (blockIdx.x * blockDim.x + threadIdx.x) >> 6;
    int lane = threadIdx.x & 63;
    if (wid >= n) return;
    const int i = wid;

    float xrv[H][2], attv[H][2];
    #pragma unroll
    for (int h = 0; h < H; h++) {
        float2 t = *(const float2*)(xr + (size_t)i * D + h * 128 + lane * 2);
        xrv[h][0] = t.x; xrv[h][1] = t.y;
        float2 a = *(const float2*)(att + h * 128 + lane * 2);
        attv[h][0] = a.x; attv[h][1] = a.y;
    }
    float m[H], dnm[H], acc[H][2];
    #pragma unroll
    for (int h = 0; h < H; h++) {
        m[h] = -INFINITY; dnm[h] = 0.f; acc[h][0] = 0.f; acc[h][1] = 0.f;
    }

    int e0 = rp[i], e1 = rp[i + 1];
    for (int e = e0; e < e1; e++) {
        int j = csrc[e];
        float xlv[H][2], part[H];
        #pragma unroll
        for (int h = 0; h < H; h++) {
            float2 t = *(const float2*)(xl + (size_t)j * D + h * 128 + lane * 2);
            xlv[h][0] = t.x; xlv[h][1] = t.y;
            float v0 = t.x + xrv[h][0];
            float v1 = t.y + xrv[h][1];
            v0 = fmaxf(v0, 0.2f * v0);
            v1 = fmaxf(v1, 0.2f * v1);
            part[h] = attv[h][0] * v0 + attv[h][1] * v1;
        }
        #pragma unroll
        for (int h = 0; h < H; h++) {
            float s = part[h];
            #pragma unroll
            for (int o = 32; o > 0; o >>= 1) s += __shfl_xor(s, o, 64);
            float mn = fmaxf(m[h], s);
            float scale = __expf(m[h] - mn);
            float p = __expf(s - mn);
            dnm[h] = dnm[h] * scale + p;
            acc[h][0] = acc[h][0] * scale + p * xlv[h][0];
            acc[h][1] = acc[h][1] * scale + p * xlv[h][1];
            m[h] = mn;
        }
    }
    #pragma unroll
    for (int h = 0; h < H; h++) {
        float inv = 1.f / dnm[h];
        #pragma unroll
        for (int q = 0; q < 2; q++) {
            int ch = h * 128 + lane * 2 + q;
            float o = acc[h][q] * inv + bias[ch];
            float vv = (o - bnm[ch]) * rsqrtf(bnv[ch] + BN_EPS) * bng[ch] + bnb[ch];
            vv = fmaxf(vv, 0.f);
            if constexpr (sizeof(OT) == 2)
                out[(size_t)i * D + ch] = (OT)f2bf(vv);
            else
                out[(size_t)i * D + ch] = vv;
        }
    }
}

// ---------------------------------------------------------- prediction head
__global__ void k_pred(const float* __restrict__ z, const int* __restrict__ pe,
                       const float* __restrict__ pr, const float* __restrict__ pert,
                       const float* __restrict__ Wp, const float* __restrict__ bp,
                       float* __restrict__ out, int P) {
    int wid = (blockIdx.x * blockDim.x + threadIdx.x) >> 6;
    int lane = threadIdx.x & 63;
    if (wid >= P) return;
    int s = pe[wid], d = pe[P + wid];
    float4 zs = *(const float4*)(z + (size_t)s * 256 + lane * 4);
    float4 zd = *(const float4*)(z + (size_t)d * 256 + lane * 4);
    float a0 = 0.f, a1 = 0.f;
    const float* zsp = (const float*)&zs;
    const float* zdp = (const float*)&zd;
    #pragma unroll
    for (int q = 0; q < 4; q++) {
        int f1 = lane * 4 + q;
        int f2 = 256 + lane * 4 + q;
        a0 += zsp[q] * Wp[f1 * 2 + 0] + zdp[q] * Wp[f2 * 2 + 0];
        a1 += zsp[q] * Wp[f1 * 2 + 1] + zdp[q] * Wp[f2 * 2 + 1];
    }
    #pragma unroll
    for (int o = 32; o > 0; o >>= 1) {
        a0 += __shfl_xor(a0, o, 64);
        a1 += __shfl_xor(a1, o, 64);
    }
    if (lane == 0) {
        float prs = pr[s], prd = pr[d], pp = pert[s] * pert[d];
        a0 += prs * Wp[512 * 2 + 0] + prd * Wp[513 * 2 + 0] + pp * Wp[514 * 2 + 0] + bp[0];
        a1 += prs * Wp[512 * 2 + 1] + prd * Wp[513 * 2 + 1] + pp * Wp[514 * 2 + 1] + bp[1];
        *(float2*)(out + (size_t)wid * 2) = make_float2(a0, a1);
    }
}

// ---------------------------------------------------------------------------

extern "C" void kernel_launch(void* const* d_in, const int* in_sizes, int n_in,
                              void* d_out, int out_size, void* d_ws, size_t ws_size,
                              hipStream_t stream) {
    const float* x    = (const float*)d_in[0];
    const int*   ei   = (const int*)d_in[1];
    const int*   pe   = (const int*)d_in[2];
    const float* pert = (const float*)d_in[3];
    const float* pr   = (const float*)d_in[4];
    const float* Wl1  = (const float*)d_in[5];
    const float* bl1  = (const float*)d_in[6];
    const float* Wr1  = (const float*)d_in[7];
    const float* br1  = (const float*)d_in[8];
    const float* att1 = (const float*)d_in[9];
    const float* bias1= (const float*)d_in[10];
    const float* bn1g = (const float*)d_in[11];
    const float* bn1b = (const float*)d_in[12];
    const float* bn1m = (const float*)d_in[13];
    const float* bn1v = (const float*)d_in[14];
    const float* Wl2  = (const float*)d_in[15];
    const float* bl2  = (const float*)d_in[16];
    const float* Wr2  = (const float*)d_in[17];
    const float* br2  = (const float*)d_in[18];
    const float* att2 = (const float*)d_in[19];
    const float* bias2= (const float*)d_in[20];
    const float* bn2g = (const float*)d_in[21];
    const float* bn2b = (const float*)d_in[22];
    const float* bn2m = (const float*)d_in[23];
    const float* bn2v = (const float*)d_in[24];
    const float* Wp   = (const float*)d_in[25];
    const float* bp   = (const float*)d_in[26];

    const int n  = in_sizes[3];          // 50000
    const int E  = in_sizes[1] / 2;      // 600000
    const int P  = in_sizes[2] / 2;      // 200000
    const int IN = in_sizes[0] / n;      // 128
    const int D1 = 512, D2 = 256;

    static float* bufA = nullptr;
    static float* bufB = nullptr;
    static short* h1b  = nullptr;
    static short* xb   = nullptr;
    static short* wt   = nullptr;
    static int *rowptr = nullptr, *bsum = nullptr, *cursor = nullptr,
               *counts = nullptr, *csrc = nullptr;
    if (!bufA) {
        hipGetSymbolAddress((void**)&bufA,   HIP_SYMBOL(g_bufA));
        hipGetSymbolAddress((void**)&bufB,   HIP_SYMBOL(g_bufB));
        hipGetSymbolAddress((void**)&h1b,    HIP_SYMBOL(g_h1b));
        hipGetSymbolAddress((void**)&xb,     HIP_SYMBOL(g_xb));
        hipGetSymbolAddress((void**)&wt,     HIP_SYMBOL(g_wt));
        hipGetSymbolAddress((void**)&rowptr, HIP_SYMBOL(g_rowptr));
        hipGetSymbolAddress((void**)&bsum,   HIP_SYMBOL(g_bsum));
        hipGetSymbolAddress((void**)&cursor, HIP_SYMBOL(g_cursor));
        hipGetSymbolAddress((void**)&counts, HIP_SYMBOL(g_counts));
        hipGetSymbolAddress((void**)&csrc,   HIP_SYMBOL(g_csrc));
    }

    float* xl1 = bufA;
    float* xr1 = bufB;
    float* xl2 = bufA;                          // reuse (lo half)
    float* xr2 = bufA + (size_t)n * D2;         // hi half
    float* z   = bufB;                          // reuse
    short* Wl1t = wt;                           // [512,128]
    short* Wr1t = wt + 65536;
    short* Wl2t = wt + 131072;                  // [256,512]
    short* Wr2t = wt + 262144;

    const int nb = (n + 255) / 256;

    // ---- CSR build
    k_init_counts<<<nb, 256, 0, stream>>>(counts, n);
    k_hist<<<(E + 255) / 256, 256, 0, stream>>>(ei, E, counts);
    k_scan1<<<nb, 256, 0, stream>>>(counts, n, rowptr, bsum);
    k_scan2<<<1, 256, 0, stream>>>(bsum, nb);
    k_scan3<<<nb, 256, 0, stream>>>(rowptr, bsum, n);
    k_fill<<<nb, 256, 0, stream>>>(rowptr, cursor, csrc, n);
    k_scatter<<<(E + 255) / 256, 256, 0, stream>>>(ei, E, cursor, csrc);

    // ---- bf16 conversions
    {
        int n4 = n * IN / 4;
        k_f32_to_bf16_v4<<<(n4 + 255) / 256, 256, 0, stream>>>(x, xb, n4);
        k_transpose_w<<<dim3(D1 / 32, IN / 32), dim3(32, 8), 0, stream>>>(Wl1, Wl1t, IN, D1);
        k_transpose_w<<<dim3(D1 / 32, IN / 32), dim3(32, 8), 0, stream>>>(Wr1, Wr1t, IN, D1);
        k_transpose_w<<<dim3(D2 / 32, D1 / 32), dim3(32, 8), 0, stream>>>(Wl2, Wl2t, D1, D2);
        k_transpose_w<<<dim3(D2 / 32, D1 / 32), dim3(32, 8), 0, stream>>>(Wr2, Wr2t, D1, D2);
    }

    const int mb = (n + 127) / 128;   // 391 row-blocks

    // ---- layer 1 GEMMs (bf16 MFMA)
    k_gemm_mfma<<<dim3(D1 / 128, mb), 256, 0, stream>>>(xb, Wl1t, bl1, xl1, n, D1, IN);
    k_gemm_mfma<<<dim3(D1 / 128, mb), 256, 0, stream>>>(xb, Wr1t, br1, xr1, n, D1, IN);
    k_gat_agg<4, short><<<(n + 3) / 4, 256, 0, stream>>>(xl1, xr1, att1, rowptr, csrc,
                                                  bias1, bn1g, bn1b, bn1m, bn1v, h1b, n);
    // ---- layer 2 GEMMs
    k_gemm_mfma<<<dim3(D2 / 128, mb), 256, 0, stream>>>(h1b, Wl2t, bl2, xl2, n, D2, D1);
    k_gemm_mfma<<<dim3(D2 / 128, mb), 256, 0, stream>>>(h1b, Wr2t, br2, xr2, n, D2, D1);
    k_gat_agg<2, float><<<(n + 3) / 4, 256, 0, stream>>>(xl2, xr2, att2, rowptr, csrc,
                                                  bias2, bn2g, bn2b, bn2m, bn2v, z, n);
    // ---- prediction head
    k_pred<<<(P + 3) / 4, 256, 0, stream>>>(z, pe, pr, pert, Wp, bp,
                                            (float*)d_out, P);
}

// Round 8
// 669.750 us; speedup vs baseline: 1.6891x; 1.2001x over previous
//
#include <hip/hip_runtime.h>
#include <math.h>

#define BN_EPS 1e-5f
#define N_NODES 50000
#define E_EDGES 600000

typedef __attribute__((ext_vector_type(8))) short bf16x8;
typedef __attribute__((ext_vector_type(4))) short bf16x4;
typedef __attribute__((ext_vector_type(4))) float f32x4;

__device__ __forceinline__ short f2bf(float f) {
    unsigned u = __float_as_uint(f);
    u += 0x7fffu + ((u >> 16) & 1u);      // RNE to bf16
    return (short)(u >> 16);
}
__device__ __forceinline__ float bf2f(short s) {
    return __uint_as_float(((unsigned)(unsigned short)s) << 16);
}

// ------------------------------------------------------------ static scratch
__device__ short g_xlb[(size_t)N_NODES * 512];    // xl1 | xl2(lo)+xr2(hi)  bf16
__device__ short g_xrb[(size_t)N_NODES * 512];    // xr1                    bf16
__device__ short g_h1b[(size_t)N_NODES * 512];    // h1                     bf16
__device__ short g_xb[(size_t)N_NODES * 128];     // x                      bf16
__device__ float g_zf[(size_t)N_NODES * 256];     // z                      f32
__device__ short g_wt[393216];                    // Wl1t|Wr1t|Wl2t|Wr2t    bf16
__device__ int   g_rowptr[N_NODES + 1];
__device__ int   g_bsum[256];
__device__ int   g_cursor[N_NODES];
__device__ int   g_counts[N_NODES];
__device__ int   g_csrc[E_EDGES + N_NODES];

// ---------------------------------------------------------------- CSR build

__global__ void k_init_counts(int* __restrict__ counts, int n) {
    int i = blockIdx.x * blockDim.x + threadIdx.x;
    if (i < n) counts[i] = 1;
}

__global__ void k_hist(const int* __restrict__ ei, int E, int* __restrict__ counts) {
    int e = blockIdx.x * blockDim.x + threadIdx.x;
    if (e < E) atomicAdd(&counts[ei[E + e]], 1);
}

__global__ void k_scan1(const int* __restrict__ counts, int n,
                        int* __restrict__ rp, int* __restrict__ bsum) {
    __shared__ int sd[256];
    int t = threadIdx.x;
    int g = blockIdx.x * 256 + t;
    int v = (g < n) ? counts[g] : 0;
    sd[t] = v;
    __syncthreads();
    for (int o = 1; o < 256; o <<= 1) {
        int u = (t >= o) ? sd[t - o] : 0;
        __syncthreads();
        sd[t] += u;
        __syncthreads();
    }
    if (g < n) rp[g + 1] = sd[t];
    if (t == 255) bsum[blockIdx.x] = sd[255];
}

__global__ void k_scan2(int* __restrict__ bsum, int nb) {
    __shared__ int sd[256];
    int t = threadIdx.x;
    int v = (t < nb) ? bsum[t] : 0;
    sd[t] = v;
    __syncthreads();
    for (int o = 1; o < 256; o <<= 1) {
        int u = (t >= o) ? sd[t - o] : 0;
        __syncthreads();
        sd[t] += u;
        __syncthreads();
    }
    if (t < nb) bsum[t] = sd[t] - v;
}

__global__ void k_scan3(int* __restrict__ rp, const int* __restrict__ bsum, int n) {
    int g = blockIdx.x * blockDim.x + threadIdx.x;
    if (g < n) rp[g + 1] += bsum[g >> 8];
    if (g == 0) rp[0] = 0;
}

__global__ void k_fill(const int* __restrict__ rp, int* __restrict__ cursor,
                       int* __restrict__ csrc, int n) {
    int i = blockIdx.x * blockDim.x + threadIdx.x;
    if (i < n) {
        int p = rp[i];
        csrc[p] = i;
        cursor[i] = p + 1;
    }
}

__global__ void k_scatter(const int* __restrict__ ei, int E,
                          int* __restrict__ cursor, int* __restrict__ csrc) {
    int e = blockIdx.x * blockDim.x + threadIdx.x;
    if (e < E) {
        int d = ei[E + e];
        int p = atomicAdd(&cursor[d], 1);
        csrc[p] = ei[e];
    }
}

// -------------------------------------------------------------- conversions

__global__ void k_f32_to_bf16_v4(const float* __restrict__ in, short* __restrict__ out,
                                 int n4) {
    int i = blockIdx.x * blockDim.x + threadIdx.x;
    if (i < n4) {
        float4 v = ((const float4*)in)[i];
        short4 o;
        o.x = f2bf(v.x); o.y = f2bf(v.y); o.z = f2bf(v.z); o.w = f2bf(v.w);
        ((short4*)out)[i] = o;
    }
}

// W [K,N] f32 -> Wt [N,K] bf16.  block (32,8)
__global__ void k_transpose_w(const float* __restrict__ W, short* __restrict__ Wt,
                              int K, int N) {
    __shared__ float s[32][33];
    int n0 = blockIdx.x * 32, k0 = blockIdx.y * 32;
    int tx = threadIdx.x, ty = threadIdx.y;
    #pragma unroll
    for (int q = 0; q < 4; q++)
        s[ty * 4 + q][tx] = W[(size_t)(k0 + ty * 4 + q) * N + n0 + tx];
    __syncthreads();
    #pragma unroll
    for (int q = 0; q < 4; q++)
        Wt[(size_t)(n0 + ty * 4 + q) * K + k0 + tx] = f2bf(s[tx][ty * 4 + q]);
}

// ------------------------------------------------------------ bf16 MFMA GEMM
// C[M,N](bf16) = A[M,K](bf16) @ Bt[N,K](bf16)^T + bias.  128x128 tile, BK=64,
// 4 waves (2x2), each wave 64x64 = 4x4 frags of 16x16x32. Padded LDS (72).
__global__ __launch_bounds__(256) void k_gemm_mfma(
    const short* __restrict__ A, const short* __restrict__ Bt,
    const float* __restrict__ bias, short* __restrict__ C,
    int M, int N, int K)
{
    __shared__ short sA[128][72];
    __shared__ short sB[128][72];
    int tid = threadIdx.x;
    int wid = tid >> 6, lane = tid & 63;
    int m0 = blockIdx.y * 128, n0 = blockIdx.x * 128;
    int wr = (wid >> 1) * 64;
    int wc = (wid & 1) * 64;
    f32x4 acc[4][4] = {};

    for (int k0 = 0; k0 < K; k0 += 64) {
        #pragma unroll
        for (int i = 0; i < 4; i++) {
            int c = tid + i * 256;
            int r = c >> 3;
            int col = (c & 7) * 8;
            bf16x8 v = {};
            int gr = m0 + r;
            if (gr < M) v = *(const bf16x8*)(A + (size_t)gr * K + k0 + col);
            *(bf16x8*)&sA[r][col] = v;
        }
        #pragma unroll
        for (int i = 0; i < 4; i++) {
            int c = tid + i * 256;
            int r = c >> 3;
            int col = (c & 7) * 8;
            bf16x8 v = *(const bf16x8*)(Bt + (size_t)(n0 + r) * K + k0 + col);
            *(bf16x8*)&sB[r][col] = v;
        }
        __syncthreads();
        #pragma unroll
        for (int kk = 0; kk < 2; kk++) {
            bf16x8 af[4], bfr[4];
            #pragma unroll
            for (int i = 0; i < 4; i++)
                af[i] = *(bf16x8*)&sA[wr + i * 16 + (lane & 15)][kk * 32 + (lane >> 4) * 8];
            #pragma unroll
            for (int j = 0; j < 4; j++)
                bfr[j] = *(bf16x8*)&sB[wc + j * 16 + (lane & 15)][kk * 32 + (lane >> 4) * 8];
            #pragma unroll
            for (int i = 0; i < 4; i++)
                #pragma unroll
                for (int j = 0; j < 4; j++)
                    acc[i][j] = __builtin_amdgcn_mfma_f32_16x16x32_bf16(
                        af[i], bfr[j], acc[i][j], 0, 0, 0);
        }
        __syncthreads();
    }
    #pragma unroll
    for (int i = 0; i < 4; i++) {
        #pragma unroll
        for (int j = 0; j < 4; j++) {
            int colg = n0 + wc + j * 16 + (lane & 15);
            float b = bias[colg];
            #pragma unroll
            for (int q = 0; q < 4; q++) {
                int rowg = m0 + wr + i * 16 + (lane >> 4) * 4 + q;
                if (rowg < M) C[(size_t)rowg * N + colg] = f2bf(acc[i][j][q] + b);
            }
        }
    }
}

// ------------------------------------------------- GATv2 flash aggregation
// One wave per dst node. Heads mapped to lane-groups of G=64/H lanes
// (H=4: 16 lanes x 8 ch; H=2: 32 lanes x 4 ch) -> all heads reduce
// concurrently in log2(G) shuffles. bf16 gather inputs. Fused bias+BN+relu.
template <int H, typename OT>
__global__ void k_gat_agg(const short* __restrict__ xl, const short* __restrict__ xr,
                          const float* __restrict__ att,
                          const int* __restrict__ rp, const int* __restrict__ csrc,
                          const float* __restrict__ bias,
                          const float* __restrict__ bng, const float* __restrict__ bnb,
                          const float* __restrict__ bnm, const float* __restrict__ bnv,
                          OT* __restrict__ out, int n) {
    constexpr int G = 64 / H;       // lanes per head group
    constexpr int CPL = 128 / G;    // channels per lane
    const int D = H * 128;
    int wid = (blockIdx.x * blockDim.x + threadIdx.x) >> 6;
    int lane = threadIdx.x & 63;
    if (wid >= n) return;
    const int i = wid;
    const int h = lane / G;
    const int ch0 = h * 128 + (lane % G) * CPL;

    float xrv[CPL], attv[CPL];
    {
        short raw[CPL];
        if constexpr (CPL == 8)
            *(bf16x8*)raw = *(const bf16x8*)(xr + (size_t)i * D + ch0);
        else
            *(bf16x4*)raw = *(const bf16x4*)(xr + (size_t)i * D + ch0);
        #pragma unroll
        for (int q = 0; q < CPL; q++) {
            xrv[q] = bf2f(raw[q]);
            attv[q] = att[ch0 + q];
        }
    }
    float m = -INFINITY, dnm = 0.f, acc[CPL] = {};

    int e0 = rp[i], e1 = rp[i + 1];
    for (int e = e0; e < e1; e++) {
        int j = csrc[e];
        float xlv[CPL];
        {
            short raw[CPL];
            if constexpr (CPL == 8)
                *(bf16x8*)raw = *(const bf16x8*)(xl + (size_t)j * D + ch0);
            else
                *(bf16x4*)raw = *(const bf16x4*)(xl + (size_t)j * D + ch0);
            #pragma unroll
            for (int q = 0; q < CPL; q++) xlv[q] = bf2f(raw[q]);
        }
        float part = 0.f;
        #pragma unroll
        for (int q = 0; q < CPL; q++) {
            float v = xlv[q] + xrv[q];
            v = fmaxf(v, 0.2f * v);
            part = fmaf(attv[q], v, part);
        }
        #pragma unroll
        for (int o = G / 2; o > 0; o >>= 1) part += __shfl_xor(part, o, 64);
        float mn = fmaxf(m, part);
        float scale = __expf(m - mn);
        float p = __expf(part - mn);
        dnm = dnm * scale + p;
        #pragma unroll
        for (int q = 0; q < CPL; q++) acc[q] = fmaf(p, xlv[q], acc[q] * scale);
        m = mn;
    }

    float inv = 1.f / dnm;
    float res[CPL];
    #pragma unroll
    for (int q = 0; q < CPL; q++) {
        int ch = ch0 + q;
        float o = acc[q] * inv + bias[ch];
        float vv = (o - bnm[ch]) * rsqrtf(bnv[ch] + BN_EPS) * bng[ch] + bnb[ch];
        res[q] = fmaxf(vv, 0.f);
    }
    if constexpr (sizeof(OT) == 2) {
        short ov[CPL];
        #pragma unroll
        for (int q = 0; q < CPL; q++) ov[q] = f2bf(res[q]);
        if constexpr (CPL == 8)
            *(bf16x8*)(out + (size_t)i * D + ch0) = *(bf16x8*)ov;
        else
            *(bf16x4*)(out + (size_t)i * D + ch0) = *(bf16x4*)ov;
    } else {
        if constexpr (CPL == 4) {
            *(float4*)((float*)out + (size_t)i * D + ch0) =
                make_float4(res[0], res[1], res[2], res[3]);
        } else {
            #pragma unroll
            for (int q = 0; q < CPL; q++) out[(size_t)i * D + ch0 + q] = res[q];
        }
    }
}

// ---------------------------------------------------------- prediction head
__global__ void k_pred(const float* __restrict__ z, const int* __restrict__ pe,
                       const float* __restrict__ pr, const float* __restrict__ pert,
                       const float* __restrict__ Wp, const float* __restrict__ bp,
                       float* __restrict__ out, int P) {
    int wid = (blockIdx.x * blockDim.x + threadIdx.x) >> 6;
    int lane = threadIdx.x & 63;
    if (wid >= P) return;
    int s = pe[wid], d = pe[P + wid];
    float4 zs = *(const float4*)(z + (size_t)s * 256 + lane * 4);
    float4 zd = *(const float4*)(z + (size_t)d * 256 + lane * 4);
    float a0 = 0.f, a1 = 0.f;
    const float* zsp = (const float*)&zs;
    const float* zdp = (const float*)&zd;
    #pragma unroll
    for (int q = 0; q < 4; q++) {
        int f1 = lane * 4 + q;
        int f2 = 256 + lane * 4 + q;
        a0 += zsp[q] * Wp[f1 * 2 + 0] + zdp[q] * Wp[f2 * 2 + 0];
        a1 += zsp[q] * Wp[f1 * 2 + 1] + zdp[q] * Wp[f2 * 2 + 1];
    }
    #pragma unroll
    for (int o = 32; o > 0; o >>= 1) {
        a0 += __shfl_xor(a0, o, 64);
        a1 += __shfl_xor(a1, o, 64);
    }
    if (lane == 0) {
        float prs = pr[s], prd = pr[d], pp = pert[s] * pert[d];
        a0 += prs * Wp[512 * 2 + 0] + prd * Wp[513 * 2 + 0] + pp * Wp[514 * 2 + 0] + bp[0];
        a1 += prs * Wp[512 * 2 + 1] + prd * Wp[513 * 2 + 1] + pp * Wp[514 * 2 + 1] + bp[1];
        *(float2*)(out + (size_t)wid * 2) = make_float2(a0, a1);
    }
}

// ---------------------------------------------------------------------------

extern "C" void kernel_launch(void* const* d_in, const int* in_sizes, int n_in,
                              void* d_out, int out_size, void* d_ws, size_t ws_size,
                              hipStream_t stream) {
    const float* x    = (const float*)d_in[0];
    const int*   ei   = (const int*)d_in[1];
    const int*   pe   = (const int*)d_in[2];
    const float* pert = (const float*)d_in[3];
    const float* pr   = (const float*)d_in[4];
    const float* Wl1  = (const float*)d_in[5];
    const float* bl1  = (const float*)d_in[6];
    const float* Wr1  = (const float*)d_in[7];
    const float* br1  = (const float*)d_in[8];
    const float* att1 = (const float*)d_in[9];
    const float* bias1= (const float*)d_in[10];
    const float* bn1g = (const float*)d_in[11];
    const float* bn1b = (const float*)d_in[12];
    const float* bn1m = (const float*)d_in[13];
    const float* bn1v = (const float*)d_in[14];
    const float* Wl2  = (const float*)d_in[15];
    const float* bl2  = (const float*)d_in[16];
    const float* Wr2  = (const float*)d_in[17];
    const float* br2  = (const float*)d_in[18];
    const float* att2 = (const float*)d_in[19];
    const float* bias2= (const float*)d_in[20];
    const float* bn2g = (const float*)d_in[21];
    const float* bn2b = (const float*)d_in[22];
    const float* bn2m = (const float*)d_in[23];
    const float* bn2v = (const float*)d_in[24];
    const float* Wp   = (const float*)d_in[25];
    const float* bp   = (const float*)d_in[26];

    const int n  = in_sizes[3];          // 50000
    const int E  = in_sizes[1] / 2;      // 600000
    const int P  = in_sizes[2] / 2;      // 200000
    const int IN = in_sizes[0] / n;      // 128
    const int D1 = 512, D2 = 256;

    static short* xlb = nullptr;
    static short* xrb = nullptr;
    static short* h1b = nullptr;
    static short* xb  = nullptr;
    static float* zf  = nullptr;
    static short* wt  = nullptr;
    static int *rowptr = nullptr, *bsum = nullptr, *cursor = nullptr,
               *counts = nullptr, *csrc = nullptr;
    if (!xlb) {
        hipGetSymbolAddress((void**)&xlb,    HIP_SYMBOL(g_xlb));
        hipGetSymbolAddress((void**)&xrb,    HIP_SYMBOL(g_xrb));
        hipGetSymbolAddress((void**)&h1b,    HIP_SYMBOL(g_h1b));
        hipGetSymbolAddress((void**)&xb,     HIP_SYMBOL(g_xb));
        hipGetSymbolAddress((void**)&zf,     HIP_SYMBOL(g_zf));
        hipGetSymbolAddress((void**)&wt,     HIP_SYMBOL(g_wt));
        hipGetSymbolAddress((void**)&rowptr, HIP_SYMBOL(g_rowptr));
        hipGetSymbolAddress((void**)&bsum,   HIP_SYMBOL(g_bsum));
        hipGetSymbolAddress((void**)&cursor, HIP_SYMBOL(g_cursor));
        hipGetSymbolAddress((void**)&counts, HIP_SYMBOL(g_counts));
        hipGetSymbolAddress((void**)&csrc,   HIP_SYMBOL(g_csrc));
    }

    short* xl1b = xlb;
    short* xr1b = xrb;
    short* xl2b = xlb;                          // reuse (lo half)
    short* xr2b = xlb + (size_t)n * D2;         // hi half
    short* Wl1t = wt;                           // [512,128]
    short* Wr1t = wt + 65536;
    short* Wl2t = wt + 131072;                  // [256,512]
    short* Wr2t = wt + 262144;

    const int nb = (n + 255) / 256;

    // ---- CSR build
    k_init_counts<<<nb, 256, 0, stream>>>(counts, n);
    k_hist<<<(E + 255) / 256, 256, 0, stream>>>(ei, E, counts);
    k_scan1<<<nb, 256, 0, stream>>>(counts, n, rowptr, bsum);
    k_scan2<<<1, 256, 0, stream>>>(bsum, nb);
    k_scan3<<<nb, 256, 0, stream>>>(rowptr, bsum, n);
    k_fill<<<nb, 256, 0, stream>>>(rowptr, cursor, csrc, n);
    k_scatter<<<(E + 255) / 256, 256, 0, stream>>>(ei, E, cursor, csrc);

    // ---- bf16 conversions
    {
        int n4 = n * IN / 4;
        k_f32_to_bf16_v4<<<(n4 + 255) / 256, 256, 0, stream>>>(x, xb, n4);
        k_transpose_w<<<dim3(D1 / 32, IN / 32), dim3(32, 8), 0, stream>>>(Wl1, Wl1t, IN, D1);
        k_transpose_w<<<dim3(D1 / 32, IN / 32), dim3(32, 8), 0, stream>>>(Wr1, Wr1t, IN, D1);
        k_transpose_w<<<dim3(D2 / 32, D1 / 32), dim3(32, 8), 0, stream>>>(Wl2, Wl2t, D1, D2);
        k_transpose_w<<<dim3(D2 / 32, D1 / 32), dim3(32, 8), 0, stream>>>(Wr2, Wr2t, D1, D2);
    }

    const int mb = (n + 127) / 128;

    // ---- layer 1
    k_gemm_mfma<<<dim3(D1 / 128, mb), 256, 0, stream>>>(xb, Wl1t, bl1, xl1b, n, D1, IN);
    k_gemm_mfma<<<dim3(D1 / 128, mb), 256, 0, stream>>>(xb, Wr1t, br1, xr1b, n, D1, IN);
    k_gat_agg<4, short><<<(n + 3) / 4, 256, 0, stream>>>(xl1b, xr1b, att1, rowptr, csrc,
                                                  bias1, bn1g, bn1b, bn1m, bn1v, h1b, n);
    // ---- layer 2
    k_gemm_mfma<<<dim3(D2 / 128, mb), 256, 0, stream>>>(h1b, Wl2t, bl2, xl2b, n, D2, D1);
    k_gemm_mfma<<<dim3(D2 / 128, mb), 256, 0, stream>>>(h1b, Wr2t, br2, xr2b, n, D2, D1);
    k_gat_agg<2, float><<<(n + 3) / 4, 256, 0, stream>>>(xl2b, xr2b, att2, rowptr, csrc,
                                                  bias2, bn2g, bn2b, bn2m, bn2v, zf, n);
    // ---- prediction head
    k_pred<<<(P + 3) / 4, 256, 0, stream>>>(zf, pe, pr, pert, Wp, bp,
                                            (float*)d_out, P);
}

// Round 9
// 638.443 us; speedup vs baseline: 1.7719x; 1.0490x over previous
//
#include <hip/hip_runtime.h>
#include <math.h>

#define BN_EPS 1e-5f
#define N_NODES 50000
#define E_EDGES 600000

typedef __attribute__((ext_vector_type(8))) short bf16x8;
typedef __attribute__((ext_vector_type(4))) short bf16x4;
typedef __attribute__((ext_vector_type(4))) float f32x4;

__device__ __forceinline__ short f2bf(float f) {
    unsigned u = __float_as_uint(f);
    u += 0x7fffu + ((u >> 16) & 1u);      // RNE to bf16
    return (short)(u >> 16);
}
__device__ __forceinline__ float bf2f(short s) {
    return __uint_as_float(((unsigned)(unsigned short)s) << 16);
}

// ------------------------------------------------------------ static scratch
__device__ short g_xlb[(size_t)N_NODES * 512];    // xl1 | xl2(lo)+xr2(hi)  bf16
__device__ short g_xrb[(size_t)N_NODES * 512];    // xr1                    bf16
__device__ short g_h1b[(size_t)N_NODES * 512];    // h1                     bf16
__device__ short g_xb[(size_t)N_NODES * 128];     // x                      bf16
__device__ float g_zf[(size_t)N_NODES * 256];     // z                      f32
__device__ short g_wt[393216];                    // Wl1t|Wr1t|Wl2t|Wr2t    bf16
__device__ int   g_rowptr[N_NODES + 1];
__device__ int   g_bsum[256];
__device__ int   g_cursor[N_NODES];
__device__ int   g_counts[N_NODES];
__device__ int   g_csrc[E_EDGES + N_NODES];

// ---------------------------------------------------------------- CSR build

__global__ void k_init_counts(int* __restrict__ counts, int n) {
    int i = blockIdx.x * blockDim.x + threadIdx.x;
    if (i < n) counts[i] = 1;
}

__global__ void k_hist(const int* __restrict__ ei, int E, int* __restrict__ counts) {
    int e = blockIdx.x * blockDim.x + threadIdx.x;
    if (e < E) atomicAdd(&counts[ei[E + e]], 1);
}

__global__ void k_scan1(const int* __restrict__ counts, int n,
                        int* __restrict__ rp, int* __restrict__ bsum) {
    __shared__ int sd[256];
    int t = threadIdx.x;
    int g = blockIdx.x * 256 + t;
    int v = (g < n) ? counts[g] : 0;
    sd[t] = v;
    __syncthreads();
    for (int o = 1; o < 256; o <<= 1) {
        int u = (t >= o) ? sd[t - o] : 0;
        __syncthreads();
        sd[t] += u;
        __syncthreads();
    }
    if (g < n) rp[g + 1] = sd[t];
    if (t == 255) bsum[blockIdx.x] = sd[255];
}

__global__ void k_scan2(int* __restrict__ bsum, int nb) {
    __shared__ int sd[256];
    int t = threadIdx.x;
    int v = (t < nb) ? bsum[t] : 0;
    sd[t] = v;
    __syncthreads();
    for (int o = 1; o < 256; o <<= 1) {
        int u = (t >= o) ? sd[t - o] : 0;
        __syncthreads();
        sd[t] += u;
        __syncthreads();
    }
    if (t < nb) bsum[t] = sd[t] - v;
}

__global__ void k_scan3(int* __restrict__ rp, const int* __restrict__ bsum, int n) {
    int g = blockIdx.x * blockDim.x + threadIdx.x;
    if (g < n) rp[g + 1] += bsum[g >> 8];
    if (g == 0) rp[0] = 0;
}

__global__ void k_fill(const int* __restrict__ rp, int* __restrict__ cursor,
                       int* __restrict__ csrc, int n) {
    int i = blockIdx.x * blockDim.x + threadIdx.x;
    if (i < n) {
        int p = rp[i];
        csrc[p] = i;
        cursor[i] = p + 1;
    }
}

__global__ void k_scatter(const int* __restrict__ ei, int E,
                          int* __restrict__ cursor, int* __restrict__ csrc) {
    int e = blockIdx.x * blockDim.x + threadIdx.x;
    if (e < E) {
        int d = ei[E + e];
        int p = atomicAdd(&cursor[d], 1);
        csrc[p] = ei[e];
    }
}

// -------------------------------------------------------------- conversions

__global__ void k_f32_to_bf16_v4(const float* __restrict__ in, short* __restrict__ out,
                                 int n4) {
    int i = blockIdx.x * blockDim.x + threadIdx.x;
    if (i < n4) {
        float4 v = ((const float4*)in)[i];
        short4 o;
        o.x = f2bf(v.x); o.y = f2bf(v.y); o.z = f2bf(v.z); o.w = f2bf(v.w);
        ((short4*)out)[i] = o;
    }
}

// W [K,N] f32 -> Wt [N,K] bf16.  block (32,8)
__global__ void k_transpose_w(const float* __restrict__ W, short* __restrict__ Wt,
                              int K, int N) {
    __shared__ float s[32][33];
    int n0 = blockIdx.x * 32, k0 = blockIdx.y * 32;
    int tx = threadIdx.x, ty = threadIdx.y;
    #pragma unroll
    for (int q = 0; q < 4; q++)
        s[ty * 4 + q][tx] = W[(size_t)(k0 + ty * 4 + q) * N + n0 + tx];
    __syncthreads();
    #pragma unroll
    for (int q = 0; q < 4; q++)
        Wt[(size_t)(n0 + ty * 4 + q) * K + k0 + tx] = f2bf(s[tx][ty * 4 + q]);
}

// -------------------------------------------------- dual-output bf16 MFMA GEMM
// Bt is [2N][K] = Wl^T stacked on Wr^T.  Block covers 128 rows x 256 cols
// (two 128-col tiles sharing the A tile).  N % 256 == 0 so each block's
// output half (Cl vs Cr) is uniform.  LDS pad 68 -> 2-way bank alias (free).
__global__ __launch_bounds__(256) void k_gemm_dual(
    const short* __restrict__ A, const short* __restrict__ Bt,
    const float* __restrict__ bias_l, const float* __restrict__ bias_r,
    short* __restrict__ Cl, short* __restrict__ Cr,
    int M, int N, int K)
{
    __shared__ short sA[128][68];
    __shared__ short sB0[128][68];
    __shared__ short sB1[128][68];
    int tid = threadIdx.x;
    int wid = tid >> 6, lane = tid & 63;
    int m0 = blockIdx.y * 128;
    int n0 = blockIdx.x * 256;              // in [0, 2N)
    int wr = (wid >> 1) * 64;
    int wc = (wid & 1) * 64;
    f32x4 acc0[4][4] = {};
    f32x4 acc1[4][4] = {};

    for (int k0 = 0; k0 < K; k0 += 64) {
        #pragma unroll
        for (int i = 0; i < 4; i++) {
            int c = tid + i * 256;
            int r = c >> 3;
            int col = (c & 7) * 8;
            bf16x8 v = {};
            int gr = m0 + r;
            if (gr < M) v = *(const bf16x8*)(A + (size_t)gr * K + k0 + col);
            *(bf16x8*)&sA[r][col] = v;
            bf16x8 b0 = *(const bf16x8*)(Bt + (size_t)(n0 + r) * K + k0 + col);
            *(bf16x8*)&sB0[r][col] = b0;
            bf16x8 b1 = *(const bf16x8*)(Bt + (size_t)(n0 + 128 + r) * K + k0 + col);
            *(bf16x8*)&sB1[r][col] = b1;
        }
        __syncthreads();
        #pragma unroll
        for (int kk = 0; kk < 2; kk++) {
            bf16x8 af[4], bf0[4], bf1[4];
            #pragma unroll
            for (int i = 0; i < 4; i++)
                af[i] = *(bf16x8*)&sA[wr + i * 16 + (lane & 15)][kk * 32 + (lane >> 4) * 8];
            #pragma unroll
            for (int j = 0; j < 4; j++) {
                bf0[j] = *(bf16x8*)&sB0[wc + j * 16 + (lane & 15)][kk * 32 + (lane >> 4) * 8];
                bf1[j] = *(bf16x8*)&sB1[wc + j * 16 + (lane & 15)][kk * 32 + (lane >> 4) * 8];
            }
            #pragma unroll
            for (int i = 0; i < 4; i++)
                #pragma unroll
                for (int j = 0; j < 4; j++) {
                    acc0[i][j] = __builtin_amdgcn_mfma_f32_16x16x32_bf16(
                        af[i], bf0[j], acc0[i][j], 0, 0, 0);
                    acc1[i][j] = __builtin_amdgcn_mfma_f32_16x16x32_bf16(
                        af[i], bf1[j], acc1[i][j], 0, 0, 0);
                }
        }
        __syncthreads();
    }
    short* outp;
    const float* bp2;
    int cb;
    if (n0 < N) { outp = Cl; bp2 = bias_l; cb = n0; }
    else        { outp = Cr; bp2 = bias_r; cb = n0 - N; }
    // C/D layout: col=lane&15, row=(lane>>4)*4+q  [verified]
    #pragma unroll
    for (int i = 0; i < 4; i++) {
        #pragma unroll
        for (int j = 0; j < 4; j++) {
            int c0 = cb + wc + j * 16 + (lane & 15);
            int c1 = c0 + 128;
            float b0 = bp2[c0];
            float b1 = bp2[c1];
            #pragma unroll
            for (int q = 0; q < 4; q++) {
                int rowg = m0 + wr + i * 16 + (lane >> 4) * 4 + q;
                if (rowg < M) {
                    outp[(size_t)rowg * N + c0] = f2bf(acc0[i][j][q] + b0);
                    outp[(size_t)rowg * N + c1] = f2bf(acc1[i][j][q] + b1);
                }
            }
        }
    }
}

// ------------------------------------------------- GATv2 flash aggregation
// One wave per dst node; heads on lane-groups of G=64/H lanes; ILP-2 over
// edges (two gathers + two reduces in flight, merged online-softmax update).
template <int H, typename OT>
__global__ void k_gat_agg(const short* __restrict__ xl, const short* __restrict__ xr,
                          const float* __restrict__ att,
                          const int* __restrict__ rp, const int* __restrict__ csrc,
                          const float* __restrict__ bias,
                          const float* __restrict__ bng, const float* __restrict__ bnb,
                          const float* __restrict__ bnm, const float* __restrict__ bnv,
                          OT* __restrict__ out, int n) {
    constexpr int G = 64 / H;       // lanes per head group
    constexpr int CPL = 128 / G;    // channels per lane
    const int D = H * 128;
    int wid = (blockIdx.x * blockDim.x + threadIdx.x) >> 6;
    int lane = threadIdx.x & 63;
    if (wid >= n) return;
    const int i = wid;
    const int h = lane / G;
    const int ch0 = h * 128 + (lane % G) * CPL;

    float xrv[CPL], attv[CPL];
    {
        short raw[CPL];
        if constexpr (CPL == 8)
            *(bf16x8*)raw = *(const bf16x8*)(xr + (size_t)i * D + ch0);
        else
            *(bf16x4*)raw = *(const bf16x4*)(xr + (size_t)i * D + ch0);
        #pragma unroll
        for (int q = 0; q < CPL; q++) {
            xrv[q] = bf2f(raw[q]);
            attv[q] = att[ch0 + q];
        }
    }
    float m = -INFINITY, dnm = 0.f, acc[CPL] = {};

    int e0 = rp[i], e1 = rp[i + 1];
    int e = e0;
    for (; e + 1 < e1; e += 2) {
        int j0 = csrc[e], j1 = csrc[e + 1];
        float xlv0[CPL], xlv1[CPL];
        {
            short r0[CPL], r1[CPL];
            if constexpr (CPL == 8) {
                *(bf16x8*)r0 = *(const bf16x8*)(xl + (size_t)j0 * D + ch0);
                *(bf16x8*)r1 = *(const bf16x8*)(xl + (size_t)j1 * D + ch0);
            } else {
                *(bf16x4*)r0 = *(const bf16x4*)(xl + (size_t)j0 * D + ch0);
                *(bf16x4*)r1 = *(const bf16x4*)(xl + (size_t)j1 * D + ch0);
            }
            #pragma unroll
            for (int q = 0; q < CPL; q++) { xlv0[q] = bf2f(r0[q]); xlv1[q] = bf2f(r1[q]); }
        }
        float p0 = 0.f, p1 = 0.f;
        #pragma unroll
        for (int q = 0; q < CPL; q++) {
            float v0 = xlv0[q] + xrv[q];
            float v1 = xlv1[q] + xrv[q];
            v0 = fmaxf(v0, 0.2f * v0);
            v1 = fmaxf(v1, 0.2f * v1);
            p0 = fmaf(attv[q], v0, p0);
            p1 = fmaf(attv[q], v1, p1);
        }
        #pragma unroll
        for (int o = G / 2; o > 0; o >>= 1) {
            p0 += __shfl_xor(p0, o, 64);
            p1 += __shfl_xor(p1, o, 64);
        }
        float mn = fmaxf(m, fmaxf(p0, p1));
        float scale = __expf(m - mn);
        float w0 = __expf(p0 - mn);
        float w1 = __expf(p1 - mn);
        dnm = dnm * scale + w0 + w1;
        #pragma unroll
        for (int q = 0; q < CPL; q++)
            acc[q] = fmaf(w1, xlv1[q], fmaf(w0, xlv0[q], acc[q] * scale));
        m = mn;
    }
    if (e < e1) {
        int j = csrc[e];
        float xlv[CPL];
        {
            short raw[CPL];
            if constexpr (CPL == 8)
                *(bf16x8*)raw = *(const bf16x8*)(xl + (size_t)j * D + ch0);
            else
                *(bf16x4*)raw = *(const bf16x4*)(xl + (size_t)j * D + ch0);
            #pragma unroll
            for (int q = 0; q < CPL; q++) xlv[q] = bf2f(raw[q]);
        }
        float part = 0.f;
        #pragma unroll
        for (int q = 0; q < CPL; q++) {
            float v = xlv[q] + xrv[q];
            v = fmaxf(v, 0.2f * v);
            part = fmaf(attv[q], v, part);
        }
        #pragma unroll
        for (int o = G / 2; o > 0; o >>= 1) part += __shfl_xor(part, o, 64);
        float mn = fmaxf(m, part);
        float scale = __expf(m - mn);
        float p = __expf(part - mn);
        dnm = dnm * scale + p;
        #pragma unroll
        for (int q = 0; q < CPL; q++) acc[q] = fmaf(p, xlv[q], acc[q] * scale);
        m = mn;
    }

    float inv = 1.f / dnm;
    float res[CPL];
    #pragma unroll
    for (int q = 0; q < CPL; q++) {
        int ch = ch0 + q;
        float o = acc[q] * inv + bias[ch];
        float vv = (o - bnm[ch]) * rsqrtf(bnv[ch] + BN_EPS) * bng[ch] + bnb[ch];
        res[q] = fmaxf(vv, 0.f);
    }
    if constexpr (sizeof(OT) == 2) {
        short ov[CPL];
        #pragma unroll
        for (int q = 0; q < CPL; q++) ov[q] = f2bf(res[q]);
        if constexpr (CPL == 8)
            *(bf16x8*)(out + (size_t)i * D + ch0) = *(bf16x8*)ov;
        else
            *(bf16x4*)(out + (size_t)i * D + ch0) = *(bf16x4*)ov;
    } else {
        if constexpr (CPL == 4) {
            *(float4*)((float*)out + (size_t)i * D + ch0) =
                make_float4(res[0], res[1], res[2], res[3]);
        } else {
            #pragma unroll
            for (int q = 0; q < CPL; q++) out[(size_t)i * D + ch0 + q] = res[q];
        }
    }
}

// ---------------------------------------------------------- prediction head
__global__ void k_pred(const float* __restrict__ z, const int* __restrict__ pe,
                       const float* __restrict__ pr, const float* __restrict__ pert,
                       const float* __restrict__ Wp, const float* __restrict__ bp,
                       float* __restrict__ out, int P) {
    int wid = (blockIdx.x * blockDim.x + threadIdx.x) >> 6;
    int lane = threadIdx.x & 63;
    if (wid >= P) return;
    int s = pe[wid], d = pe[P + wid];
    float4 zs = *(const float4*)(z + (size_t)s * 256 + lane * 4);
    float4 zd = *(const float4*)(z + (size_t)d * 256 + lane * 4);
    float a0 = 0.f, a1 = 0.f;
    const float* zsp = (const float*)&zs;
    const float* zdp = (const float*)&zd;
    #pragma unroll
    for (int q = 0; q < 4; q++) {
        int f1 = lane * 4 + q;
        int f2 = 256 + lane * 4 + q;
        a0 += zsp[q] * Wp[f1 * 2 + 0] + zdp[q] * Wp[f2 * 2 + 0];
        a1 += zsp[q] * Wp[f1 * 2 + 1] + zdp[q] * Wp[f2 * 2 + 1];
    }
    #pragma unroll
    for (int o = 32; o > 0; o >>= 1) {
        a0 += __shfl_xor(a0, o, 64);
        a1 += __shfl_xor(a1, o, 64);
    }
    if (lane == 0) {
        float prs = pr[s], prd = pr[d], pp = pert[s] * pert[d];
        a0 += prs * Wp[512 * 2 + 0] + prd * Wp[513 * 2 + 0] + pp * Wp[514 * 2 + 0] + bp[0];
        a1 += prs * Wp[512 * 2 + 1] + prd * Wp[513 * 2 + 1] + pp * Wp[514 * 2 + 1] + bp[1];
        *(float2*)(out + (size_t)wid * 2) = make_float2(a0, a1);
    }
}

// ---------------------------------------------------------------------------

extern "C" void kernel_launch(void* const* d_in, const int* in_sizes, int n_in,
                              void* d_out, int out_size, void* d_ws, size_t ws_size,
                              hipStream_t stream) {
    const float* x    = (const float*)d_in[0];
    const int*   ei   = (const int*)d_in[1];
    const int*   pe   = (const int*)d_in[2];
    const float* pert = (const float*)d_in[3];
    const float* pr   = (const float*)d_in[4];
    const float* Wl1  = (const float*)d_in[5];
    const float* bl1  = (const float*)d_in[6];
    const float* Wr1  = (const float*)d_in[7];
    const float* br1  = (const float*)d_in[8];
    const float* att1 = (const float*)d_in[9];
    const float* bias1= (const float*)d_in[10];
    const float* bn1g = (const float*)d_in[11];
    const float* bn1b = (const float*)d_in[12];
    const float* bn1m = (const float*)d_in[13];
    const float* bn1v = (const float*)d_in[14];
    const float* Wl2  = (const float*)d_in[15];
    const float* bl2  = (const float*)d_in[16];
    const float* Wr2  = (const float*)d_in[17];
    const float* br2  = (const float*)d_in[18];
    const float* att2 = (const float*)d_in[19];
    const float* bias2= (const float*)d_in[20];
    const float* bn2g = (const float*)d_in[21];
    const float* bn2b = (const float*)d_in[22];
    const float* bn2m = (const float*)d_in[23];
    const float* bn2v = (const float*)d_in[24];
    const float* Wp   = (const float*)d_in[25];
    const float* bp   = (const float*)d_in[26];

    const int n  = in_sizes[3];          // 50000
    const int E  = in_sizes[1] / 2;      // 600000
    const int P  = in_sizes[2] / 2;      // 200000
    const int IN = in_sizes[0] / n;      // 128
    const int D1 = 512, D2 = 256;

    static short* xlb = nullptr;
    static short* xrb = nullptr;
    static short* h1b = nullptr;
    static short* xb  = nullptr;
    static float* zf  = nullptr;
    static short* wt  = nullptr;
    static int *rowptr = nullptr, *bsum = nullptr, *cursor = nullptr,
               *counts = nullptr, *csrc = nullptr;
    if (!xlb) {
        hipGetSymbolAddress((void**)&xlb,    HIP_SYMBOL(g_xlb));
        hipGetSymbolAddress((void**)&xrb,    HIP_SYMBOL(g_xrb));
        hipGetSymbolAddress((void**)&h1b,    HIP_SYMBOL(g_h1b));
        hipGetSymbolAddress((void**)&xb,     HIP_SYMBOL(g_xb));
        hipGetSymbolAddress((void**)&zf,     HIP_SYMBOL(g_zf));
        hipGetSymbolAddress((void**)&wt,     HIP_SYMBOL(g_wt));
        hipGetSymbolAddress((void**)&rowptr, HIP_SYMBOL(g_rowptr));
        hipGetSymbolAddress((void**)&bsum,   HIP_SYMBOL(g_bsum));
        hipGetSymbolAddress((void**)&cursor, HIP_SYMBOL(g_cursor));
        hipGetSymbolAddress((void**)&counts, HIP_SYMBOL(g_counts));
        hipGetSymbolAddress((void**)&csrc,   HIP_SYMBOL(g_csrc));
    }

    short* xl1b = xlb;
    short* xr1b = xrb;
    short* xl2b = xlb;                          // reuse (lo half)
    short* xr2b = xlb + (size_t)n * D2;         // hi half
    short* WtL1 = wt;                           // stacked [1024][128]
    short* WtL2 = wt + 131072;                  // stacked [512][512]
    short* Wl1t = wt;
    short* Wr1t = wt + 65536;
    short* Wl2t = wt + 131072;
    short* Wr2t = wt + 262144;

    const int nb = (n + 255) / 256;

    // ---- CSR build
    k_init_counts<<<nb, 256, 0, stream>>>(counts, n);
    k_hist<<<(E + 255) / 256, 256, 0, stream>>>(ei, E, counts);
    k_scan1<<<nb, 256, 0, stream>>>(counts, n, rowptr, bsum);
    k_scan2<<<1, 256, 0, stream>>>(bsum, nb);
    k_scan3<<<nb, 256, 0, stream>>>(rowptr, bsum, n);
    k_fill<<<nb, 256, 0, stream>>>(rowptr, cursor, csrc, n);
    k_scatter<<<(E + 255) / 256, 256, 0, stream>>>(ei, E, cursor, csrc);

    // ---- bf16 conversions
    {
        int n4 = n * IN / 4;
        k_f32_to_bf16_v4<<<(n4 + 255) / 256, 256, 0, stream>>>(x, xb, n4);
        k_transpose_w<<<dim3(D1 / 32, IN / 32), dim3(32, 8), 0, stream>>>(Wl1, Wl1t, IN, D1);
        k_transpose_w<<<dim3(D1 / 32, IN / 32), dim3(32, 8), 0, stream>>>(Wr1, Wr1t, IN, D1);
        k_transpose_w<<<dim3(D2 / 32, D1 / 32), dim3(32, 8), 0, stream>>>(Wl2, Wl2t, D1, D2);
        k_transpose_w<<<dim3(D2 / 32, D1 / 32), dim3(32, 8), 0, stream>>>(Wr2, Wr2t, D1, D2);
    }

    const int mb = (n + 127) / 128;

    // ---- layer 1 (fused dual GEMM: 2N=1024 cols -> 4 col-blocks)
    k_gemm_dual<<<dim3(2 * D1 / 256, mb), 256, 0, stream>>>(
        xb, WtL1, bl1, br1, xl1b, xr1b, n, D1, IN);
    k_gat_agg<4, short><<<(n + 3) / 4, 256, 0, stream>>>(xl1b, xr1b, att1, rowptr, csrc,
                                                  bias1, bn1g, bn1b, bn1m, bn1v, h1b, n);
    // ---- layer 2 (fused dual GEMM: 2N=512 cols -> 2 col-blocks)
    k_gemm_dual<<<dim3(2 * D2 / 256, mb), 256, 0, stream>>>(
        h1b, WtL2, bl2, br2, xl2b, xr2b, n, D2, D1);
    k_gat_agg<2, float><<<(n + 3) / 4, 256, 0, stream>>>(xl2b, xr2b, att2, rowptr, csrc,
                                                  bias2, bn2g, bn2b, bn2m, bn2v, zf, n);
    // ---- prediction head
    k_pred<<<(P + 3) / 4, 256, 0, stream>>>(zf, pe, pr, pert, Wp, bp,
                                            (float*)d_out, P);
}

// Round 12
// 625.792 us; speedup vs baseline: 1.8078x; 1.0202x over previous
//
#include <hip/hip_runtime.h>
#include <math.h>

#define BN_EPS 1e-5f
#define N_NODES 50000
#define E_EDGES 600000

typedef __attribute__((ext_vector_type(8))) short bf16x8;
typedef __attribute__((ext_vector_type(4))) short bf16x4;
typedef __attribute__((ext_vector_type(4))) float f32x4;

__device__ __forceinline__ short f2bf(float f) {
    unsigned u = __float_as_uint(f);
    u += 0x7fffu + ((u >> 16) & 1u);      // RNE to bf16
    return (short)(u >> 16);
}
__device__ __forceinline__ float bf2f(short s) {
    return __uint_as_float(((unsigned)(unsigned short)s) << 16);
}

// ------------------------------------------------------------ static scratch
__device__ short g_xlb[(size_t)N_NODES * 512];    // xl1 | xl2(lo)+xr2(hi)  bf16
__device__ short g_xrb[(size_t)N_NODES * 512];    // xr1                    bf16
__device__ short g_h1b[(size_t)N_NODES * 512];    // h1                     bf16
__device__ short g_xb[(size_t)N_NODES * 128];     // x                      bf16
__device__ short g_zb[(size_t)N_NODES * 256];     // z                      bf16
__device__ short g_wt[393216];                    // Wl1t|Wr1t|Wl2t|Wr2t    bf16
__device__ int   g_rowptr[N_NODES + 1];
__device__ int   g_bsum[256];
__device__ int   g_cursor[N_NODES];
__device__ int   g_counts[N_NODES];
__device__ int   g_csrc[E_EDGES + N_NODES];

// ---------------------------------------------------------------- CSR build

__global__ void k_init_counts(int* __restrict__ counts, int n) {
    int i = blockIdx.x * blockDim.x + threadIdx.x;
    if (i < n) counts[i] = 1;
}

__global__ void k_hist(const int* __restrict__ ei, int E, int* __restrict__ counts) {
    int e = blockIdx.x * blockDim.x + threadIdx.x;
    if (e < E) atomicAdd(&counts[ei[E + e]], 1);
}

__global__ void k_scan1(const int* __restrict__ counts, int n,
                        int* __restrict__ rp, int* __restrict__ bsum) {
    __shared__ int sd[256];
    int t = threadIdx.x;
    int g = blockIdx.x * 256 + t;
    int v = (g < n) ? counts[g] : 0;
    sd[t] = v;
    __syncthreads();
    for (int o = 1; o < 256; o <<= 1) {
        int u = (t >= o) ? sd[t - o] : 0;
        __syncthreads();
        sd[t] += u;
        __syncthreads();
    }
    if (g < n) rp[g + 1] = sd[t];
    if (t == 255) bsum[blockIdx.x] = sd[255];
}

__global__ void k_scan2(int* __restrict__ bsum, int nb) {
    __shared__ int sd[256];
    int t = threadIdx.x;
    int v = (t < nb) ? bsum[t] : 0;
    sd[t] = v;
    __syncthreads();
    for (int o = 1; o < 256; o <<= 1) {
        int u = (t >= o) ? sd[t - o] : 0;
        __syncthreads();
        sd[t] += u;
        __syncthreads();
    }
    if (t < nb) bsum[t] = sd[t] - v;
}

__global__ void k_scan3(int* __restrict__ rp, const int* __restrict__ bsum, int n) {
    int g = blockIdx.x * blockDim.x + threadIdx.x;
    if (g < n) rp[g + 1] += bsum[g >> 8];
    if (g == 0) rp[0] = 0;
}

__global__ void k_fill(const int* __restrict__ rp, int* __restrict__ cursor,
                       int* __restrict__ csrc, int n) {
    int i = blockIdx.x * blockDim.x + threadIdx.x;
    if (i < n) {
        int p = rp[i];
        csrc[p] = i;
        cursor[i] = p + 1;
    }
}

__global__ void k_scatter(const int* __restrict__ ei, int E,
                          int* __restrict__ cursor, int* __restrict__ csrc) {
    int e = blockIdx.x * blockDim.x + threadIdx.x;
    if (e < E) {
        int d = ei[E + e];
        int p = atomicAdd(&cursor[d], 1);
        csrc[p] = ei[e];
    }
}

// -------------------------------------------------------------- conversions

__global__ void k_f32_to_bf16_v4(const float* __restrict__ in, short* __restrict__ out,
                                 int n4) {
    int i = blockIdx.x * blockDim.x + threadIdx.x;
    if (i < n4) {
        float4 v = ((const float4*)in)[i];
        short4 o;
        o.x = f2bf(v.x); o.y = f2bf(v.y); o.z = f2bf(v.z); o.w = f2bf(v.w);
        ((short4*)out)[i] = o;
    }
}

// W [K,N] f32 -> Wt [N,K] bf16.  block (32,8)
__global__ void k_transpose_w(const float* __restrict__ W, short* __restrict__ Wt,
                              int K, int N) {
    __shared__ float s[32][33];
    int n0 = blockIdx.x * 32, k0 = blockIdx.y * 32;
    int tx = threadIdx.x, ty = threadIdx.y;
    #pragma unroll
    for (int q = 0; q < 4; q++)
        s[ty * 4 + q][tx] = W[(size_t)(k0 + ty * 4 + q) * N + n0 + tx];
    __syncthreads();
    #pragma unroll
    for (int q = 0; q < 4; q++)
        Wt[(size_t)(n0 + ty * 4 + q) * K + k0 + tx] = f2bf(s[tx][ty * 4 + q]);
}

// -------------------------------------------------- dual-output bf16 MFMA GEMM
// Bt is [2N][K] = Wl^T stacked on Wr^T.  Block: 128 rows x 256 cols (two
// 128-col tiles share the A tile).  MFMA operands SWAPPED (mfma(b,a,acc)) so
// each lane holds 4 consecutive output COLS -> bf16x4 (8B) stores:
//   m = m0+wr+i*16+(lane&15),  n = cb+wc+j*16+(lane>>4)*4+q
__global__ __launch_bounds__(256) void k_gemm_dual(
    const short* __restrict__ A, const short* __restrict__ Bt,
    const float* __restrict__ bias_l, const float* __restrict__ bias_r,
    short* __restrict__ Cl, short* __restrict__ Cr,
    int M, int N, int K)
{
    __shared__ short sA[128][68];
    __shared__ short sB0[128][68];
    __shared__ short sB1[128][68];
    int tid = threadIdx.x;
    int wid = tid >> 6, lane = tid & 63;
    int m0 = blockIdx.y * 128;
    int n0 = blockIdx.x * 256;              // in [0, 2N)
    int wr = (wid >> 1) * 64;
    int wc = (wid & 1) * 64;
    f32x4 acc0[4][4] = {};
    f32x4 acc1[4][4] = {};

    for (int k0 = 0; k0 < K; k0 += 64) {
        #pragma unroll
        for (int i = 0; i < 4; i++) {
            int c = tid + i * 256;
            int r = c >> 3;
            int col = (c & 7) * 8;
            bf16x8 v = {};
            int gr = m0 + r;
            if (gr < M) v = *(const bf16x8*)(A + (size_t)gr * K + k0 + col);
            *(bf16x8*)&sA[r][col] = v;
            bf16x8 b0 = *(const bf16x8*)(Bt + (size_t)(n0 + r) * K + k0 + col);
            *(bf16x8*)&sB0[r][col] = b0;
            bf16x8 b1 = *(const bf16x8*)(Bt + (size_t)(n0 + 128 + r) * K + k0 + col);
            *(bf16x8*)&sB1[r][col] = b1;
        }
        __syncthreads();
        #pragma unroll
        for (int kk = 0; kk < 2; kk++) {
            bf16x8 af[4], bf0[4], bf1[4];
            #pragma unroll
            for (int i = 0; i < 4; i++)
                af[i] = *(bf16x8*)&sA[wr + i * 16 + (lane & 15)][kk * 32 + (lane >> 4) * 8];
            #pragma unroll
            for (int j = 0; j < 4; j++) {
                bf0[j] = *(bf16x8*)&sB0[wc + j * 16 + (lane & 15)][kk * 32 + (lane >> 4) * 8];
                bf1[j] = *(bf16x8*)&sB1[wc + j * 16 + (lane & 15)][kk * 32 + (lane >> 4) * 8];
            }
            #pragma unroll
            for (int i = 0; i < 4; i++)
                #pragma unroll
                for (int j = 0; j < 4; j++) {
                    acc0[i][j] = __builtin_amdgcn_mfma_f32_16x16x32_bf16(
                        bf0[j], af[i], acc0[i][j], 0, 0, 0);
                    acc1[i][j] = __builtin_amdgcn_mfma_f32_16x16x32_bf16(
                        bf1[j], af[i], acc1[i][j], 0, 0, 0);
                }
        }
        __syncthreads();
    }
    short* outp;
    const float* bp2;
    int cb;
    if (n0 < N) { outp = Cl; bp2 = bias_l; cb = n0; }
    else        { outp = Cr; bp2 = bias_r; cb = n0 - N; }
    #pragma unroll
    for (int i = 0; i < 4; i++) {
        int rowg = m0 + wr + i * 16 + (lane & 15);
        if (rowg >= M) continue;
        #pragma unroll
        for (int j = 0; j < 4; j++) {
            int nl = cb + wc + j * 16 + (lane >> 4) * 4;
            float4 b0 = *(const float4*)(bp2 + nl);
            float4 b1 = *(const float4*)(bp2 + nl + 128);
            short o0[4], o1[4];
            o0[0] = f2bf(acc0[i][j][0] + b0.x); o0[1] = f2bf(acc0[i][j][1] + b0.y);
            o0[2] = f2bf(acc0[i][j][2] + b0.z); o0[3] = f2bf(acc0[i][j][3] + b0.w);
            o1[0] = f2bf(acc1[i][j][0] + b1.x); o1[1] = f2bf(acc1[i][j][1] + b1.y);
            o1[2] = f2bf(acc1[i][j][2] + b1.z); o1[3] = f2bf(acc1[i][j][3] + b1.w);
            *(bf16x4*)(outp + (size_t)rowg * N + nl)       = *(bf16x4*)o0;
            *(bf16x4*)(outp + (size_t)rowg * N + nl + 128) = *(bf16x4*)o1;
        }
    }
}

// ------------------------------------------------- GATv2 flash aggregation
// One wave per dst node; heads on lane-groups of G=64/H lanes; ILP-2 over
// edges (two gathers + two reduces in flight, merged online-softmax update).
template <int H, typename OT>
__global__ void k_gat_agg(const short* __restrict__ xl, const short* __restrict__ xr,
                          const float* __restrict__ att,
                          const int* __restrict__ rp, const int* __restrict__ csrc,
                          const float* __restrict__ bias,
                          const float* __restrict__ bng, const float* __restrict__ bnb,
                          const float* __restrict__ bnm, const float* __restrict__ bnv,
                          OT* __restrict__ out, int n) {
    constexpr int G = 64 / H;       // lanes per head group
    constexpr int CPL = 128 / G;    // channels per lane
    const int D = H * 128;
    int wid = (blockIdx.x * blockDim.x + threadIdx.x) >> 6;
    int lane = threadIdx.x & 63;
    if (wid >= n) return;
    const int i = wid;
    const int h = lane / G;
    const int ch0 = h * 128 + (lane % G) * CPL;

    float xrv[CPL], attv[CPL];
    {
        short raw[CPL];
        if constexpr (CPL == 8)
            *(bf16x8*)raw = *(const bf16x8*)(xr + (size_t)i * D + ch0);
        else
            *(bf16x4*)raw = *(const bf16x4*)(xr + (size_t)i * D + ch0);
        #pragma unroll
        for (int q = 0; q < CPL; q++) {
            xrv[q] = bf2f(raw[q]);
            attv[q] = att[ch0 + q];
        }
    }
    float m = -INFINITY, dnm = 0.f, acc[CPL] = {};

    int e0 = rp[i], e1 = rp[i + 1];
    int e = e0;
    for (; e + 1 < e1; e += 2) {
        int j0 = csrc[e], j1 = csrc[e + 1];
        float xlv0[CPL], xlv1[CPL];
        {
            short r0[CPL], r1[CPL];
            if constexpr (CPL == 8) {
                *(bf16x8*)r0 = *(const bf16x8*)(xl + (size_t)j0 * D + ch0);
                *(bf16x8*)r1 = *(const bf16x8*)(xl + (size_t)j1 * D + ch0);
            } else {
                *(bf16x4*)r0 = *(const bf16x4*)(xl + (size_t)j0 * D + ch0);
                *(bf16x4*)r1 = *(const bf16x4*)(xl + (size_t)j1 * D + ch0);
            }
            #pragma unroll
            for (int q = 0; q < CPL; q++) { xlv0[q] = bf2f(r0[q]); xlv1[q] = bf2f(r1[q]); }
        }
        float p0 = 0.f, p1 = 0.f;
        #pragma unroll
        for (int q = 0; q < CPL; q++) {
            float v0 = xlv0[q] + xrv[q];
            float v1 = xlv1[q] + xrv[q];
            v0 = fmaxf(v0, 0.2f * v0);
            v1 = fmaxf(v1, 0.2f * v1);
            p0 = fmaf(attv[q], v0, p0);
            p1 = fmaf(attv[q], v1, p1);
        }
        #pragma unroll
        for (int o = G / 2; o > 0; o >>= 1) {
            p0 += __shfl_xor(p0, o, 64);
            p1 += __shfl_xor(p1, o, 64);
        }
        float mn = fmaxf(m, fmaxf(p0, p1));
        float scale = __expf(m - mn);
        float w0 = __expf(p0 - mn);
        float w1 = __expf(p1 - mn);
        dnm = dnm * scale + w0 + w1;
        #pragma unroll
        for (int q = 0; q < CPL; q++)
            acc[q] = fmaf(w1, xlv1[q], fmaf(w0, xlv0[q], acc[q] * scale));
        m = mn;
    }
    if (e < e1) {
        int j = csrc[e];
        float xlv[CPL];
        {
            short raw[CPL];
            if constexpr (CPL == 8)
                *(bf16x8*)raw = *(const bf16x8*)(xl + (size_t)j * D + ch0);
            else
                *(bf16x4*)raw = *(const bf16x4*)(xl + (size_t)j * D + ch0);
            #pragma unroll
            for (int q = 0; q < CPL; q++) xlv[q] = bf2f(raw[q]);
        }
        float part = 0.f;
        #pragma unroll
        for (int q = 0; q < CPL; q++) {
            float v = xlv[q] + xrv[q];
            v = fmaxf(v, 0.2f * v);
            part = fmaf(attv[q], v, part);
        }
        #pragma unroll
        for (int o = G / 2; o > 0; o >>= 1) part += __shfl_xor(part, o, 64);
        float mn = fmaxf(m, part);
        float scale = __expf(m - mn);
        float p = __expf(part - mn);
        dnm = dnm * scale + p;
        #pragma unroll
        for (int q = 0; q < CPL; q++) acc[q] = fmaf(p, xlv[q], acc[q] * scale);
        m = mn;
    }

    float inv = 1.f / dnm;
    float res[CPL];
    #pragma unroll
    for (int q = 0; q < CPL; q++) {
        int ch = ch0 + q;
        float o = acc[q] * inv + bias[ch];
        float vv = (o - bnm[ch]) * rsqrtf(bnv[ch] + BN_EPS) * bng[ch] + bnb[ch];
        res[q] = fmaxf(vv, 0.f);
    }
    if constexpr (sizeof(OT) == 2) {
        short ov[CPL];
        #pragma unroll
        for (int q = 0; q < CPL; q++) ov[q] = f2bf(res[q]);
        if constexpr (CPL == 8)
            *(bf16x8*)(out + (size_t)i * D + ch0) = *(bf16x8*)ov;
        else
            *(bf16x4*)(out + (size_t)i * D + ch0) = *(bf16x4*)ov;
    } else {
        #pragma unroll
        for (int q = 0; q < CPL; q++) out[(size_t)i * D + ch0 + q] = res[q];
    }
}

// ---------------------------------------------------------- prediction head
// z is bf16 [n][256].  One wave per pred edge: lanes 0-31 read z[s] (8 ch
// each), lanes 32-63 read z[d]; full-wave reduce; lane 0 adds scalar tail.
__global__ void k_pred(const short* __restrict__ z, const int* __restrict__ pe,
                       const float* __restrict__ pr, const float* __restrict__ pert,
                       const float* __restrict__ Wp, const float* __restrict__ bp,
                       float* __restrict__ out, int P) {
    int wid = (blockIdx.x * blockDim.x + threadIdx.x) >> 6;
    int lane = threadIdx.x & 63;
    if (wid >= P) return;
    int s = pe[wid], d = pe[P + wid];
    int node = (lane < 32) ? s : d;
    int off = (lane & 31) * 8;
    short raw[8];
    *(bf16x8*)raw = *(const bf16x8*)(z + (size_t)node * 256 + off);
    int fbase = (lane < 32) ? off : 256 + off;
    float a0 = 0.f, a1 = 0.f;
    #pragma unroll
    for (int q = 0; q < 8; q++) {
        float v = bf2f(raw[q]);
        a0 = fmaf(v, Wp[(fbase + q) * 2 + 0], a0);
        a1 = fmaf(v, Wp[(fbase + q) * 2 + 1], a1);
    }
    #pragma unroll
    for (int o = 32; o > 0; o >>= 1) {
        a0 += __shfl_xor(a0, o, 64);
        a1 += __shfl_xor(a1, o, 64);
    }
    if (lane == 0) {
        float prs = pr[s], prd = pr[d], pp = pert[s] * pert[d];
        a0 += prs * Wp[512 * 2 + 0] + prd * Wp[513 * 2 + 0] + pp * Wp[514 * 2 + 0] + bp[0];
        a1 += prs * Wp[512 * 2 + 1] + prd * Wp[513 * 2 + 1] + pp * Wp[514 * 2 + 1] + bp[1];
        *(float2*)(out + (size_t)wid * 2) = make_float2(a0, a1);
    }
}

// ---------------------------------------------------------------------------

extern "C" void kernel_launch(void* const* d_in, const int* in_sizes, int n_in,
                              void* d_out, int out_size, void* d_ws, size_t ws_size,
                              hipStream_t stream) {
    const float* x    = (const float*)d_in[0];
    const int*   ei   = (const int*)d_in[1];
    const int*   pe   = (const int*)d_in[2];
    const float* pert = (const float*)d_in[3];
    const float* pr   = (const float*)d_in[4];
    const float* Wl1  = (const float*)d_in[5];
    const float* bl1  = (const float*)d_in[6];
    const float* Wr1  = (const float*)d_in[7];
    const float* br1  = (const float*)d_in[8];
    const float* att1 = (const float*)d_in[9];
    const float* bias1= (const float*)d_in[10];
    const float* bn1g = (const float*)d_in[11];
    const float* bn1b = (const float*)d_in[12];
    const float* bn1m = (const float*)d_in[13];
    const float* bn1v = (const float*)d_in[14];
    const float* Wl2  = (const float*)d_in[15];
    const float* bl2  = (const float*)d_in[16];
    const float* Wr2  = (const float*)d_in[17];
    const float* br2  = (const float*)d_in[18];
    const float* att2 = (const float*)d_in[19];
    const float* bias2= (const float*)d_in[20];
    const float* bn2g = (const float*)d_in[21];
    const float* bn2b = (const float*)d_in[22];
    const float* bn2m = (const float*)d_in[23];
    const float* bn2v = (const float*)d_in[24];
    const float* Wp   = (const float*)d_in[25];
    const float* bp   = (const float*)d_in[26];

    const int n  = in_sizes[3];          // 50000
    const int E  = in_sizes[1] / 2;      // 600000
    const int P  = in_sizes[2] / 2;      // 200000
    const int IN = in_sizes[0] / n;      // 128
    const int D1 = 512, D2 = 256;

    static short* xlb = nullptr;
    static short* xrb = nullptr;
    static short* h1b = nullptr;
    static short* xb  = nullptr;
    static short* zb  = nullptr;
    static short* wt  = nullptr;
    static int *rowptr = nullptr, *bsum = nullptr, *cursor = nullptr,
               *counts = nullptr, *csrc = nullptr;
    if (!xlb) {
        hipGetSymbolAddress((void**)&xlb,    HIP_SYMBOL(g_xlb));
        hipGetSymbolAddress((void**)&xrb,    HIP_SYMBOL(g_xrb));
        hipGetSymbolAddress((void**)&h1b,    HIP_SYMBOL(g_h1b));
        hipGetSymbolAddress((void**)&xb,     HIP_SYMBOL(g_xb));
        hipGetSymbolAddress((void**)&zb,     HIP_SYMBOL(g_zb));
        hipGetSymbolAddress((void**)&wt,     HIP_SYMBOL(g_wt));
        hipGetSymbolAddress((void**)&rowptr, HIP_SYMBOL(g_rowptr));
        hipGetSymbolAddress((void**)&bsum,   HIP_SYMBOL(g_bsum));
        hipGetSymbolAddress((void**)&cursor, HIP_SYMBOL(g_cursor));
        hipGetSymbolAddress((void**)&counts, HIP_SYMBOL(g_counts));
        hipGetSymbolAddress((void**)&csrc,   HIP_SYMBOL(g_csrc));
    }

    short* xl1b = xlb;
    short* xr1b = xrb;
    short* xl2b = xlb;                          // reuse (lo half)
    short* xr2b = xlb + (size_t)n * D2;         // hi half
    short* WtL1 = wt;                           // stacked [1024][128]
    short* WtL2 = wt + 131072;                  // stacked [512][512]
    short* Wl1t = wt;
    short* Wr1t = wt + 65536;
    short* Wl2t = wt + 131072;
    short* Wr2t = wt + 262144;

    const int nb = (n + 255) / 256;

    // ---- CSR build
    k_init_counts<<<nb, 256, 0, stream>>>(counts, n);
    k_hist<<<(E + 255) / 256, 256, 0, stream>>>(ei, E, counts);
    k_scan1<<<nb, 256, 0, stream>>>(counts, n, rowptr, bsum);
    k_scan2<<<1, 256, 0, stream>>>(bsum, nb);
    k_scan3<<<nb, 256, 0, stream>>>(rowptr, bsum, n);
    k_fill<<<nb, 256, 0, stream>>>(rowptr, cursor, csrc, n);
    k_scatter<<<(E + 255) / 256, 256, 0, stream>>>(ei, E, cursor, csrc);

    // ---- bf16 conversions
    {
        int n4 = n * IN / 4;
        k_f32_to_bf16_v4<<<(n4 + 255) / 256, 256, 0, stream>>>(x, xb, n4);
        k_transpose_w<<<dim3(D1 / 32, IN / 32), dim3(32, 8), 0, stream>>>(Wl1, Wl1t, IN, D1);
        k_transpose_w<<<dim3(D1 / 32, IN / 32), dim3(32, 8), 0, stream>>>(Wr1, Wr1t, IN, D1);
        k_transpose_w<<<dim3(D2 / 32, D1 / 32), dim3(32, 8), 0, stream>>>(Wl2, Wl2t, D1, D2);
        k_transpose_w<<<dim3(D2 / 32, D1 / 32), dim3(32, 8), 0, stream>>>(Wr2, Wr2t, D1, D2);
    }

    const int mb = (n + 127) / 128;

    // ---- layer 1 (fused dual GEMM: 2N=1024 cols -> 4 col-blocks)
    k_gemm_dual<<<dim3(2 * D1 / 256, mb), 256, 0, stream>>>(
        xb, WtL1, bl1, br1, xl1b, xr1b, n, D1, IN);
    k_gat_agg<4, short><<<(n + 3) / 4, 256, 0, stream>>>(xl1b, xr1b, att1, rowptr, csrc,
                                                  bias1, bn1g, bn1b, bn1m, bn1v, h1b, n);
    // ---- layer 2 (fused dual GEMM: 2N=512 cols -> 2 col-blocks)
    k_gemm_dual<<<dim3(2 * D2 / 256, mb), 256, 0, stream>>>(
        h1b, WtL2, bl2, br2, xl2b, xr2b, n, D2, D1);
    k_gat_agg<2, short><<<(n + 3) / 4, 256, 0, stream>>>(xl2b, xr2b, att2, rowptr, csrc,
                                                  bias2, bn2g, bn2b, bn2m, bn2v, zb, n);
    // ---- prediction head
    k_pred<<<(P + 3) / 4, 256, 0, stream>>>(zb, pe, pr, pert, Wp, bp,
                                            (float*)d_out, P);
}

// Round 13
// 617.490 us; speedup vs baseline: 1.8321x; 1.0134x over previous
//
#include <hip/hip_runtime.h>
#include <math.h>

#define BN_EPS 1e-5f
#define N_NODES 50000
#define M_PAD   50048            // 391 * 128, removes all M-guards in GEMM
#define E_EDGES 600000

typedef __attribute__((ext_vector_type(8))) short bf16x8;
typedef __attribute__((ext_vector_type(4))) short bf16x4;
typedef __attribute__((ext_vector_type(4))) float f32x4;

__device__ __forceinline__ short f2bf(float f) {
    unsigned u = __float_as_uint(f);
    u += 0x7fffu + ((u >> 16) & 1u);      // RNE to bf16
    return (short)(u >> 16);
}
__device__ __forceinline__ float bf2f(short s) {
    return __uint_as_float(((unsigned)(unsigned short)s) << 16);
}
__device__ __forceinline__ void gload_lds16(const short* g, short* l) {
    __builtin_amdgcn_global_load_lds((const __attribute__((address_space(1))) void*)g,
                                     (__attribute__((address_space(3))) void*)l, 16, 0, 0);
}

// ------------------------------------------------------------ static scratch
__device__ short g_xlb[(size_t)M_PAD * 512];      // xl1 | xl2(lo)+xr2(hi)  bf16
__device__ short g_xrb[(size_t)M_PAD * 512];      // xr1                    bf16
__device__ short g_h1b[(size_t)M_PAD * 512];      // h1                     bf16
__device__ short g_xb[(size_t)M_PAD * 128];       // x                      bf16
__device__ short g_zb[(size_t)M_PAD * 256];       // z                      bf16
__device__ short g_wt[393216];                    // Wl1t|Wr1t|Wl2t|Wr2t    bf16
__device__ int   g_rowptr[N_NODES + 1];
__device__ int   g_bsum[256];
__device__ int   g_cursor[N_NODES];
__device__ int   g_counts[N_NODES];
__device__ int   g_csrc[E_EDGES + N_NODES];

// ---------------------------------------------------------------- CSR build

__global__ void k_init_counts(int* __restrict__ counts, int n) {
    int i = blockIdx.x * blockDim.x + threadIdx.x;
    if (i < n) counts[i] = 1;
}

__global__ void k_hist(const int* __restrict__ ei, int E, int* __restrict__ counts) {
    int e = blockIdx.x * blockDim.x + threadIdx.x;
    if (e < E) atomicAdd(&counts[ei[E + e]], 1);
}

__global__ void k_scan1(const int* __restrict__ counts, int n,
                        int* __restrict__ rp, int* __restrict__ bsum) {
    __shared__ int sd[256];
    int t = threadIdx.x;
    int g = blockIdx.x * 256 + t;
    int v = (g < n) ? counts[g] : 0;
    sd[t] = v;
    __syncthreads();
    for (int o = 1; o < 256; o <<= 1) {
        int u = (t >= o) ? sd[t - o] : 0;
        __syncthreads();
        sd[t] += u;
        __syncthreads();
    }
    if (g < n) rp[g + 1] = sd[t];
    if (t == 255) bsum[blockIdx.x] = sd[255];
}

__global__ void k_scan2(int* __restrict__ bsum, int nb) {
    __shared__ int sd[256];
    int t = threadIdx.x;
    int v = (t < nb) ? bsum[t] : 0;
    sd[t] = v;
    __syncthreads();
    for (int o = 1; o < 256; o <<= 1) {
        int u = (t >= o) ? sd[t - o] : 0;
        __syncthreads();
        sd[t] += u;
        __syncthreads();
    }
    if (t < nb) bsum[t] = sd[t] - v;
}

__global__ void k_scan3(int* __restrict__ rp, const int* __restrict__ bsum, int n) {
    int g = blockIdx.x * blockDim.x + threadIdx.x;
    if (g < n) rp[g + 1] += bsum[g >> 8];
    if (g == 0) rp[0] = 0;
}

__global__ void k_fill(const int* __restrict__ rp, int* __restrict__ cursor,
                       int* __restrict__ csrc, int n) {
    int i = blockIdx.x * blockDim.x + threadIdx.x;
    if (i < n) {
        int p = rp[i];
        csrc[p] = i;
        cursor[i] = p + 1;
    }
}

__global__ void k_scatter(const int* __restrict__ ei, int E,
                          int* __restrict__ cursor, int* __restrict__ csrc) {
    int e = blockIdx.x * blockDim.x + threadIdx.x;
    if (e < E) {
        int d = ei[E + e];
        int p = atomicAdd(&cursor[d], 1);
        csrc[p] = ei[e];
    }
}

// -------------------------------------------------------------- conversions

__global__ void k_f32_to_bf16_v4(const float* __restrict__ in, short* __restrict__ out,
                                 int n4) {
    int i = blockIdx.x * blockDim.x + threadIdx.x;
    if (i < n4) {
        float4 v = ((const float4*)in)[i];
        short4 o;
        o.x = f2bf(v.x); o.y = f2bf(v.y); o.z = f2bf(v.z); o.w = f2bf(v.w);
        ((short4*)out)[i] = o;
    }
}

// W [K,N] f32 -> Wt [N,K] bf16.  block (32,8)
__global__ void k_transpose_w(const float* __restrict__ W, short* __restrict__ Wt,
                              int K, int N) {
    __shared__ float s[32][33];
    int n0 = blockIdx.x * 32, k0 = blockIdx.y * 32;
    int tx = threadIdx.x, ty = threadIdx.y;
    #pragma unroll
    for (int q = 0; q < 4; q++)
        s[ty * 4 + q][tx] = W[(size_t)(k0 + ty * 4 + q) * N + n0 + tx];
    __syncthreads();
    #pragma unroll
    for (int q = 0; q < 4; q++)
        Wt[(size_t)(n0 + ty * 4 + q) * K + k0 + tx] = f2bf(s[tx][ty * 4 + q]);
}

// -------------------------------------------------- dual-output bf16 MFMA GEMM
// Bt [2N][K] = Wl^T stacked on Wr^T.  Block 128 rows x 256 cols; all row
// buffers padded to M_PAD so no M-guards.  Staging: global_load_lds width=16
// into LINEAR LDS [128][64]; XOR swizzle chunk^=(row&7) applied on the GLOBAL
// source and again on the ds_read address (both-sides pattern) -> conflict-
// free b128 reads.  MFMA operands swapped: lane holds 4 consecutive out COLS.
__global__ __launch_bounds__(256) void k_gemm_dual(
    const short* __restrict__ A, const short* __restrict__ Bt,
    const float* __restrict__ bias_l, const float* __restrict__ bias_r,
    short* __restrict__ Cl, short* __restrict__ Cr,
    int N, int K)
{
    __shared__ short sA[128][64];
    __shared__ short sB0[128][64];
    __shared__ short sB1[128][64];
    int tid = threadIdx.x;
    int wid = tid >> 6, lane = tid & 63;
    int m0 = blockIdx.y * 128;
    int n0 = blockIdx.x * 256;              // in [0, 2N)
    int wr = (wid >> 1) * 64;
    int wc = (wid & 1) * 64;
    // staging geometry: inst i covers tile rows (wid*4+i)*8 .. +7;
    // lane l -> row = rg0 + (l>>3), dst chunk = l&7, src chunk = (l&7)^(row&7)
    int rowL = wid * 32 + (lane >> 3);      // row for inst i: rowL + i*8
    int chunk = lane & 7;

    f32x4 acc0[4][4] = {};
    f32x4 acc1[4][4] = {};

    for (int k0 = 0; k0 < K; k0 += 64) {
        #pragma unroll
        for (int i = 0; i < 4; i++) {
            int row = rowL + i * 8;
            int cs = chunk ^ (row & 7);
            const short* ga = A  + ((size_t)(m0 + row) * K + k0 + cs * 8);
            const short* g0 = Bt + ((size_t)(n0 + row) * K + k0 + cs * 8);
            const short* g1 = Bt + ((size_t)(n0 + 128 + row) * K + k0 + cs * 8);
            gload_lds16(ga, &sA[wid * 32 + i * 8][0]);
            gload_lds16(g0, &sB0[wid * 32 + i * 8][0]);
            gload_lds16(g1, &sB1[wid * 32 + i * 8][0]);
        }
        __syncthreads();
        #pragma unroll
        for (int kk = 0; kk < 2; kk++) {
            bf16x8 af[4], bf0[4], bf1[4];
            #pragma unroll
            for (int i = 0; i < 4; i++) {
                int r = wr + i * 16 + (lane & 15);
                int c = ((kk * 4 + (lane >> 4)) ^ (r & 7)) << 3;
                af[i] = *(bf16x8*)&sA[r][c];
            }
            #pragma unroll
            for (int j = 0; j < 4; j++) {
                int r = wc + j * 16 + (lane & 15);
                int c = ((kk * 4 + (lane >> 4)) ^ (r & 7)) << 3;
                bf0[j] = *(bf16x8*)&sB0[r][c];
                bf1[j] = *(bf16x8*)&sB1[r][c];
            }
            #pragma unroll
            for (int i = 0; i < 4; i++)
                #pragma unroll
                for (int j = 0; j < 4; j++) {
                    acc0[i][j] = __builtin_amdgcn_mfma_f32_16x16x32_bf16(
                        bf0[j], af[i], acc0[i][j], 0, 0, 0);
                    acc1[i][j] = __builtin_amdgcn_mfma_f32_16x16x32_bf16(
                        bf1[j], af[i], acc1[i][j], 0, 0, 0);
                }
        }
        __syncthreads();
    }
    short* outp;
    const float* bp2;
    int cb;
    if (n0 < N) { outp = Cl; bp2 = bias_l; cb = n0; }
    else        { outp = Cr; bp2 = bias_r; cb = n0 - N; }
    #pragma unroll
    for (int i = 0; i < 4; i++) {
        int rowg = m0 + wr + i * 16 + (lane & 15);
        #pragma unroll
        for (int j = 0; j < 4; j++) {
            int nl = cb + wc + j * 16 + (lane >> 4) * 4;
            float4 b0 = *(const float4*)(bp2 + nl);
            float4 b1 = *(const float4*)(bp2 + nl + 128);
            short o0[4], o1[4];
            o0[0] = f2bf(acc0[i][j][0] + b0.x); o0[1] = f2bf(acc0[i][j][1] + b0.y);
            o0[2] = f2bf(acc0[i][j][2] + b0.z); o0[3] = f2bf(acc0[i][j][3] + b0.w);
            o1[0] = f2bf(acc1[i][j][0] + b1.x); o1[1] = f2bf(acc1[i][j][1] + b1.y);
            o1[2] = f2bf(acc1[i][j][2] + b1.z); o1[3] = f2bf(acc1[i][j][3] + b1.w);
            *(bf16x4*)(outp + (size_t)rowg * N + nl)       = *(bf16x4*)o0;
            *(bf16x4*)(outp + (size_t)rowg * N + nl + 128) = *(bf16x4*)o1;
        }
    }
}

// ------------------------------------------------- GATv2 flash aggregation
// One wave per dst node; heads on lane-groups of G=64/H lanes; ILP-4 over
// edges (four gathers + reduces in flight, one merged online-softmax update).
template <int H, typename OT>
__global__ void k_gat_agg(const short* __restrict__ xl, const short* __restrict__ xr,
                          const float* __restrict__ att,
                          const int* __restrict__ rp, const int* __restrict__ csrc,
                          const float* __restrict__ bias,
                          const float* __restrict__ bng, const float* __restrict__ bnb,
                          const float* __restrict__ bnm, const float* __restrict__ bnv,
                          OT* __restrict__ out, int n) {
    constexpr int G = 64 / H;       // lanes per head group
    constexpr int CPL = 128 / G;    // channels per lane
    const int D = H * 128;
    int wid = (blockIdx.x * blockDim.x + threadIdx.x) >> 6;
    int lane = threadIdx.x & 63;
    if (wid >= n) return;
    const int i = wid;
    const int h = lane / G;
    const int ch0 = h * 128 + (lane % G) * CPL;

    float xrv[CPL], attv[CPL];
    {
        short raw[CPL];
        if constexpr (CPL == 8)
            *(bf16x8*)raw = *(const bf16x8*)(xr + (size_t)i * D + ch0);
        else
            *(bf16x4*)raw = *(const bf16x4*)(xr + (size_t)i * D + ch0);
        #pragma unroll
        for (int q = 0; q < CPL; q++) {
            xrv[q] = bf2f(raw[q]);
            attv[q] = att[ch0 + q];
        }
    }
    float m = -INFINITY, dnm = 0.f, acc[CPL] = {};

    int e0 = rp[i], e1 = rp[i + 1];
    int e = e0;
    for (; e + 3 < e1; e += 4) {
        int j0 = csrc[e], j1 = csrc[e + 1], j2 = csrc[e + 2], j3 = csrc[e + 3];
        float x0[CPL], x1[CPL], x2[CPL], x3[CPL];
        {
            short r0[CPL], r1[CPL], r2[CPL], r3[CPL];
            if constexpr (CPL == 8) {
                *(bf16x8*)r0 = *(const bf16x8*)(xl + (size_t)j0 * D + ch0);
                *(bf16x8*)r1 = *(const bf16x8*)(xl + (size_t)j1 * D + ch0);
                *(bf16x8*)r2 = *(const bf16x8*)(xl + (size_t)j2 * D + ch0);
                *(bf16x8*)r3 = *(const bf16x8*)(xl + (size_t)j3 * D + ch0);
            } else {
                *(bf16x4*)r0 = *(const bf16x4*)(xl + (size_t)j0 * D + ch0);
                *(bf16x4*)r1 = *(const bf16x4*)(xl + (size_t)j1 * D + ch0);
                *(bf16x4*)r2 = *(const bf16x4*)(xl + (size_t)j2 * D + ch0);
                *(bf16x4*)r3 = *(const bf16x4*)(xl + (size_t)j3 * D + ch0);
            }
            #pragma unroll
            for (int q = 0; q < CPL; q++) {
                x0[q] = bf2f(r0[q]); x1[q] = bf2f(r1[q]);
                x2[q] = bf2f(r2[q]); x3[q] = bf2f(r3[q]);
            }
        }
        float p0 = 0.f, p1 = 0.f, p2 = 0.f, p3 = 0.f;
        #pragma unroll
        for (int q = 0; q < CPL; q++) {
            float v0 = x0[q] + xrv[q], v1 = x1[q] + xrv[q];
            float v2 = x2[q] + xrv[q], v3 = x3[q] + xrv[q];
            v0 = fmaxf(v0, 0.2f * v0); v1 = fmaxf(v1, 0.2f * v1);
            v2 = fmaxf(v2, 0.2f * v2); v3 = fmaxf(v3, 0.2f * v3);
            p0 = fmaf(attv[q], v0, p0); p1 = fmaf(attv[q], v1, p1);
            p2 = fmaf(attv[q], v2, p2); p3 = fmaf(attv[q], v3, p3);
        }
        #pragma unroll
        for (int o = G / 2; o > 0; o >>= 1) {
            p0 += __shfl_xor(p0, o, 64);
            p1 += __shfl_xor(p1, o, 64);
            p2 += __shfl_xor(p2, o, 64);
            p3 += __shfl_xor(p3, o, 64);
        }
        float mn = fmaxf(fmaxf(fmaxf(p0, p1), fmaxf(p2, p3)), m);
        float scale = __expf(m - mn);
        float w0 = __expf(p0 - mn), w1 = __expf(p1 - mn);
        float w2 = __expf(p2 - mn), w3 = __expf(p3 - mn);
        dnm = dnm * scale + (w0 + w1) + (w2 + w3);
        #pragma unroll
        for (int q = 0; q < CPL; q++) {
            float a = fmaf(w0, x0[q], acc[q] * scale);
            a = fmaf(w1, x1[q], a);
            a = fmaf(w2, x2[q], a);
            acc[q] = fmaf(w3, x3[q], a);
        }
        m = mn;
    }
    for (; e < e1; e++) {
        int j = csrc[e];
        float xlv[CPL];
        {
            short raw[CPL];
            if constexpr (CPL == 8)
                *(bf16x8*)raw = *(const bf16x8*)(xl + (size_t)j * D + ch0);
            else
                *(bf16x4*)raw = *(const bf16x4*)(xl + (size_t)j * D + ch0);
            #pragma unroll
            for (int q = 0; q < CPL; q++) xlv[q] = bf2f(raw[q]);
        }
        float part = 0.f;
        #pragma unroll
        for (int q = 0; q < CPL; q++) {
            float v = xlv[q] + xrv[q];
            v = fmaxf(v, 0.2f * v);
            part = fmaf(attv[q], v, part);
        }
        #pragma unroll
        for (int o = G / 2; o > 0; o >>= 1) part += __shfl_xor(part, o, 64);
        float mn = fmaxf(m, part);
        float scale = __expf(m - mn);
        float p = __expf(part - mn);
        dnm = dnm * scale + p;
        #pragma unroll
        for (int q = 0; q < CPL; q++) acc[q] = fmaf(p, xlv[q], acc[q] * scale);
        m = mn;
    }

    float inv = 1.f / dnm;
    float res[CPL];
    #pragma unroll
    for (int q = 0; q < CPL; q++) {
        int ch = ch0 + q;
        float o = acc[q] * inv + bias[ch];
        float vv = (o - bnm[ch]) * rsqrtf(bnv[ch] + BN_EPS) * bng[ch] + bnb[ch];
        res[q] = fmaxf(vv, 0.f);
    }
    if constexpr (sizeof(OT) == 2) {
        short ov[CPL];
        #pragma unroll
        for (int q = 0; q < CPL; q++) ov[q] = f2bf(res[q]);
        if constexpr (CPL == 8)
            *(bf16x8*)(out + (size_t)i * D + ch0) = *(bf16x8*)ov;
        else
            *(bf16x4*)(out + (size_t)i * D + ch0) = *(bf16x4*)ov;
    } else {
        #pragma unroll
        for (int q = 0; q < CPL; q++) out[(size_t)i * D + ch0 + q] = res[q];
    }
}

// ---------------------------------------------------------- prediction head
// z is bf16 [n][256].  One wave per pred edge: lanes 0-31 read z[s] (8 ch
// each), lanes 32-63 read z[d]; full-wave reduce; lane 0 adds scalar tail.
__global__ void k_pred(const short* __restrict__ z, const int* __restrict__ pe,
                       const float* __restrict__ pr, const float* __restrict__ pert,
                       const float* __restrict__ Wp, const float* __restrict__ bp,
                       float* __restrict__ out, int P) {
    int wid = (blockIdx.x * blockDim.x + threadIdx.x) >> 6;
    int lane = threadIdx.x & 63;
    if (wid >= P) return;
    int s = pe[wid], d = pe[P + wid];
    int node = (lane < 32) ? s : d;
    int off = (lane & 31) * 8;
    short raw[8];
    *(bf16x8*)raw = *(const bf16x8*)(z + (size_t)node * 256 + off);
    int fbase = (lane < 32) ? off : 256 + off;
    float a0 = 0.f, a1 = 0.f;
    #pragma unroll
    for (int q = 0; q < 8; q++) {
        float v = bf2f(raw[q]);
        a0 = fmaf(v, Wp[(fbase + q) * 2 + 0], a0);
        a1 = fmaf(v, Wp[(fbase + q) * 2 + 1], a1);
    }
    #pragma unroll
    for (int o = 32; o > 0; o >>= 1) {
        a0 += __shfl_xor(a0, o, 64);
        a1 += __shfl_xor(a1, o, 64);
    }
    if (lane == 0) {
        float prs = pr[s], prd = pr[d], pp = pert[s] * pert[d];
        a0 += prs * Wp[512 * 2 + 0] + prd * Wp[513 * 2 + 0] + pp * Wp[514 * 2 + 0] + bp[0];
        a1 += prs * Wp[512 * 2 + 1] + prd * Wp[513 * 2 + 1] + pp * Wp[514 * 2 + 1] + bp[1];
        *(float2*)(out + (size_t)wid * 2) = make_float2(a0, a1);
    }
}

// ---------------------------------------------------------------------------

extern "C" void kernel_launch(void* const* d_in, const int* in_sizes, int n_in,
                              void* d_out, int out_size, void* d_ws, size_t ws_size,
                              hipStream_t stream) {
    const float* x    = (const float*)d_in[0];
    const int*   ei   = (const int*)d_in[1];
    const int*   pe   = (const int*)d_in[2];
    const float* pert = (const float*)d_in[3];
    const float* pr   = (const float*)d_in[4];
    const float* Wl1  = (const float*)d_in[5];
    const float* bl1  = (const float*)d_in[6];
    const float* Wr1  = (const float*)d_in[7];
    const float* br1  = (const float*)d_in[8];
    const float* att1 = (const float*)d_in[9];
    const float* bias1= (const float*)d_in[10];
    const float* bn1g = (const float*)d_in[11];
    const float* bn1b = (const float*)d_in[12];
    const float* bn1m = (const float*)d_in[13];
    const float* bn1v = (const float*)d_in[14];
    const float* Wl2  = (const float*)d_in[15];
    const float* bl2  = (const float*)d_in[16];
    const float* Wr2  = (const float*)d_in[17];
    const float* br2  = (const float*)d_in[18];
    const float* att2 = (const float*)d_in[19];
    const float* bias2= (const float*)d_in[20];
    const float* bn2g = (const float*)d_in[21];
    const float* bn2b = (const float*)d_in[22];
    const float* bn2m = (const float*)d_in[23];
    const float* bn2v = (const float*)d_in[24];
    const float* Wp   = (const float*)d_in[25];
    const float* bp   = (const float*)d_in[26];

    const int n  = in_sizes[3];          // 50000
    const int E  = in_sizes[1] / 2;      // 600000
    const int P  = in_sizes[2] / 2;      // 200000
    const int IN = in_sizes[0] / n;      // 128
    const int D1 = 512, D2 = 256;

    static short* xlb = nullptr;
    static short* xrb = nullptr;
    static short* h1b = nullptr;
    static short* xb  = nullptr;
    static short* zb  = nullptr;
    static short* wt  = nullptr;
    static int *rowptr = nullptr, *bsum = nullptr, *cursor = nullptr,
               *counts = nullptr, *csrc = nullptr;
    if (!xlb) {
        hipGetSymbolAddress((void**)&xlb,    HIP_SYMBOL(g_xlb));
        hipGetSymbolAddress((void**)&xrb,    HIP_SYMBOL(g_xrb));
        hipGetSymbolAddress((void**)&h1b,    HIP_SYMBOL(g_h1b));
        hipGetSymbolAddress((void**)&xb,     HIP_SYMBOL(g_xb));
        hipGetSymbolAddress((void**)&zb,     HIP_SYMBOL(g_zb));
        hipGetSymbolAddress((void**)&wt,     HIP_SYMBOL(g_wt));
        hipGetSymbolAddress((void**)&rowptr, HIP_SYMBOL(g_rowptr));
        hipGetSymbolAddress((void**)&bsum,   HIP_SYMBOL(g_bsum));
        hipGetSymbolAddress((void**)&cursor, HIP_SYMBOL(g_cursor));
        hipGetSymbolAddress((void**)&counts, HIP_SYMBOL(g_counts));
        hipGetSymbolAddress((void**)&csrc,   HIP_SYMBOL(g_csrc));
    }

    short* xl1b = xlb;
    short* xr1b = xrb;
    short* xl2b = xlb;                              // reuse (lo half)
    short* xr2b = xlb + (size_t)M_PAD * D2;         // hi half (padded stride)
    short* WtL1 = wt;                               // stacked [1024][128]
    short* WtL2 = wt + 131072;                      // stacked [512][512]
    short* Wl1t = wt;
    short* Wr1t = wt + 65536;
    short* Wl2t = wt + 131072;
    short* Wr2t = wt + 262144;

    const int nb = (n + 255) / 256;

    // ---- CSR build
    k_init_counts<<<nb, 256, 0, stream>>>(counts, n);
    k_hist<<<(E + 255) / 256, 256, 0, stream>>>(ei, E, counts);
    k_scan1<<<nb, 256, 0, stream>>>(counts, n, rowptr, bsum);
    k_scan2<<<1, 256, 0, stream>>>(bsum, nb);
    k_scan3<<<nb, 256, 0, stream>>>(rowptr, bsum, n);
    k_fill<<<nb, 256, 0, stream>>>(rowptr, cursor, csrc, n);
    k_scatter<<<(E + 255) / 256, 256, 0, stream>>>(ei, E, cursor, csrc);

    // ---- bf16 conversions
    {
        int n4 = n * IN / 4;
        k_f32_to_bf16_v4<<<(n4 + 255) / 256, 256, 0, stream>>>(x, xb, n4);
        k_transpose_w<<<dim3(D1 / 32, IN / 32), dim3(32, 8), 0, stream>>>(Wl1, Wl1t, IN, D1);
        k_transpose_w<<<dim3(D1 / 32, IN / 32), dim3(32, 8), 0, stream>>>(Wr1, Wr1t, IN, D1);
        k_transpose_w<<<dim3(D2 / 32, D1 / 32), dim3(32, 8), 0, stream>>>(Wl2, Wl2t, D1, D2);
        k_transpose_w<<<dim3(D2 / 32, D1 / 32), dim3(32, 8), 0, stream>>>(Wr2, Wr2t, D1, D2);
    }

    const int mb = M_PAD / 128;   // 391

    // ---- layer 1 (fused dual GEMM: 2N=1024 cols -> 4 col-blocks)
    k_gemm_dual<<<dim3(2 * D1 / 256, mb), 256, 0, stream>>>(
        xb, WtL1, bl1, br1, xl1b, xr1b, D1, IN);
    k_gat_agg<4, short><<<(n + 3) / 4, 256, 0, stream>>>(xl1b, xr1b, att1, rowptr, csrc,
                                                  bias1, bn1g, bn1b, bn1m, bn1v, h1b, n);
    // ---- layer 2 (fused dual GEMM: 2N=512 cols -> 2 col-blocks)
    k_gemm_dual<<<dim3(2 * D2 / 256, mb), 256, 0, stream>>>(
        h1b, WtL2, bl2, br2, xl2b, xr2b, D2, D1);
    k_gat_agg<2, short><<<(n + 3) / 4, 256, 0, stream>>>(xl2b, xr2b, att2, rowptr, csrc,
                                                  bias2, bn2g, bn2b, bn2m, bn2v, zb, n);
    // ---- prediction head
    k_pred<<<(P + 3) / 4, 256, 0, stream>>>(zb, pe, pr, pert, Wp, bp,
                                            (float*)d_out, P);
}

// Round 14
// 572.179 us; speedup vs baseline: 1.9772x; 1.0792x over previous
//
#include <hip/hip_runtime.h>
#include <math.h>

#define BN_EPS 1e-5f
#define N_NODES 50000
#define M_PAD   50048            // 391 * 128, removes all M-guards in GEMM
#define E_EDGES 600000

typedef __attribute__((ext_vector_type(8))) short bf16x8;
typedef __attribute__((ext_vector_type(4))) short bf16x4;
typedef __attribute__((ext_vector_type(4))) float f32x4;

__device__ __forceinline__ short f2bf(float f) {
    unsigned u = __float_as_uint(f);
    u += 0x7fffu + ((u >> 16) & 1u);      // RNE to bf16
    return (short)(u >> 16);
}
__device__ __forceinline__ float bf2f(short s) {
    return __uint_as_float(((unsigned)(unsigned short)s) << 16);
}
__device__ __forceinline__ void gload_lds16(const short* g, short* l) {
    __builtin_amdgcn_global_load_lds((const __attribute__((address_space(1))) void*)g,
                                     (__attribute__((address_space(3))) void*)l, 16, 0, 0);
}

// ------------------------------------------------------------ static scratch
__device__ short g_xlb[(size_t)M_PAD * 512];      // xl1 | xl2(lo)+xr2(hi)  bf16
__device__ short g_xrb[(size_t)M_PAD * 512];      // xr1                    bf16
__device__ short g_h1b[(size_t)M_PAD * 512];      // h1                     bf16
__device__ short g_xb[(size_t)M_PAD * 128];       // x                      bf16
__device__ short g_zb[(size_t)M_PAD * 256];       // z                      bf16
__device__ float g_y[(size_t)M_PAD * 4];          // per-node proj (f32x4)
__device__ short g_wt[393216];                    // Wl1t|Wr1t|Wl2t|Wr2t    bf16
__device__ int   g_rowptr[N_NODES + 1];
__device__ int   g_bsum[256];
__device__ int   g_cursor[N_NODES];
__device__ int   g_counts[N_NODES];
__device__ int   g_csrc[E_EDGES + N_NODES];

// ---------------------------------------------------------------- CSR build

__global__ void k_init_counts(int* __restrict__ counts, int n) {
    int i = blockIdx.x * blockDim.x + threadIdx.x;
    if (i < n) counts[i] = 1;
}

__global__ void k_hist(const int* __restrict__ ei, int E, int* __restrict__ counts) {
    int e = blockIdx.x * blockDim.x + threadIdx.x;
    if (e < E) atomicAdd(&counts[ei[E + e]], 1);
}

__global__ void k_scan1(const int* __restrict__ counts, int n,
                        int* __restrict__ rp, int* __restrict__ bsum) {
    __shared__ int sd[256];
    int t = threadIdx.x;
    int g = blockIdx.x * 256 + t;
    int v = (g < n) ? counts[g] : 0;
    sd[t] = v;
    __syncthreads();
    for (int o = 1; o < 256; o <<= 1) {
        int u = (t >= o) ? sd[t - o] : 0;
        __syncthreads();
        sd[t] += u;
        __syncthreads();
    }
    if (g < n) rp[g + 1] = sd[t];
    if (t == 255) bsum[blockIdx.x] = sd[255];
}

__global__ void k_scan2(int* __restrict__ bsum, int nb) {
    __shared__ int sd[256];
    int t = threadIdx.x;
    int v = (t < nb) ? bsum[t] : 0;
    sd[t] = v;
    __syncthreads();
    for (int o = 1; o < 256; o <<= 1) {
        int u = (t >= o) ? sd[t - o] : 0;
        __syncthreads();
        sd[t] += u;
        __syncthreads();
    }
    if (t < nb) bsum[t] = sd[t] - v;
}

__global__ void k_scan3(int* __restrict__ rp, const int* __restrict__ bsum, int n) {
    int g = blockIdx.x * blockDim.x + threadIdx.x;
    if (g < n) rp[g + 1] += bsum[g >> 8];
    if (g == 0) rp[0] = 0;
}

__global__ void k_fill(const int* __restrict__ rp, int* __restrict__ cursor,
                       int* __restrict__ csrc, int n) {
    int i = blockIdx.x * blockDim.x + threadIdx.x;
    if (i < n) {
        int p = rp[i];
        csrc[p] = i;
        cursor[i] = p + 1;
    }
}

__global__ void k_scatter(const int* __restrict__ ei, int E,
                          int* __restrict__ cursor, int* __restrict__ csrc) {
    int e = blockIdx.x * blockDim.x + threadIdx.x;
    if (e < E) {
        int d = ei[E + e];
        int p = atomicAdd(&cursor[d], 1);
        csrc[p] = ei[e];
    }
}

// -------------------------------------------------------------- conversions

__global__ void k_f32_to_bf16_v4(const float* __restrict__ in, short* __restrict__ out,
                                 int n4) {
    int i = blockIdx.x * blockDim.x + threadIdx.x;
    if (i < n4) {
        float4 v = ((const float4*)in)[i];
        short4 o;
        o.x = f2bf(v.x); o.y = f2bf(v.y); o.z = f2bf(v.z); o.w = f2bf(v.w);
        ((short4*)out)[i] = o;
    }
}

// W [K,N] f32 -> Wt [N,K] bf16.  block (32,8)
__global__ void k_transpose_w(const float* __restrict__ W, short* __restrict__ Wt,
                              int K, int N) {
    __shared__ float s[32][33];
    int n0 = blockIdx.x * 32, k0 = blockIdx.y * 32;
    int tx = threadIdx.x, ty = threadIdx.y;
    #pragma unroll
    for (int q = 0; q < 4; q++)
        s[ty * 4 + q][tx] = W[(size_t)(k0 + ty * 4 + q) * N + n0 + tx];
    __syncthreads();
    #pragma unroll
    for (int q = 0; q < 4; q++)
        Wt[(size_t)(n0 + ty * 4 + q) * K + k0 + tx] = f2bf(s[tx][ty * 4 + q]);
}

// -------------------------------------------------- dual-output bf16 MFMA GEMM
// Bt [2N][K] = Wl^T stacked on Wr^T.  Block 128 rows x 256 cols; all row
// buffers padded to M_PAD so no M-guards.  Staging: global_load_lds width=16
// into LINEAR LDS [128][64]; XOR swizzle chunk^=(row&7) applied on the GLOBAL
// source and again on the ds_read address (both-sides pattern) -> conflict-
// free b128 reads.  MFMA operands swapped: lane holds 4 consecutive out COLS.
__global__ __launch_bounds__(256) void k_gemm_dual(
    const short* __restrict__ A, const short* __restrict__ Bt,
    const float* __restrict__ bias_l, const float* __restrict__ bias_r,
    short* __restrict__ Cl, short* __restrict__ Cr,
    int N, int K)
{
    __shared__ short sA[128][64];
    __shared__ short sB0[128][64];
    __shared__ short sB1[128][64];
    int tid = threadIdx.x;
    int wid = tid >> 6, lane = tid & 63;
    int m0 = blockIdx.y * 128;
    int n0 = blockIdx.x * 256;              // in [0, 2N)
    int wr = (wid >> 1) * 64;
    int wc = (wid & 1) * 64;
    int rowL = wid * 32 + (lane >> 3);      // row for inst i: rowL + i*8
    int chunk = lane & 7;

    f32x4 acc0[4][4] = {};
    f32x4 acc1[4][4] = {};

    for (int k0 = 0; k0 < K; k0 += 64) {
        #pragma unroll
        for (int i = 0; i < 4; i++) {
            int row = rowL + i * 8;
            int cs = chunk ^ (row & 7);
            const short* ga = A  + ((size_t)(m0 + row) * K + k0 + cs * 8);
            const short* g0 = Bt + ((size_t)(n0 + row) * K + k0 + cs * 8);
            const short* g1 = Bt + ((size_t)(n0 + 128 + row) * K + k0 + cs * 8);
            gload_lds16(ga, &sA[wid * 32 + i * 8][0]);
            gload_lds16(g0, &sB0[wid * 32 + i * 8][0]);
            gload_lds16(g1, &sB1[wid * 32 + i * 8][0]);
        }
        __syncthreads();
        #pragma unroll
        for (int kk = 0; kk < 2; kk++) {
            bf16x8 af[4], bf0[4], bf1[4];
            #pragma unroll
            for (int i = 0; i < 4; i++) {
                int r = wr + i * 16 + (lane & 15);
                int c = ((kk * 4 + (lane >> 4)) ^ (r & 7)) << 3;
                af[i] = *(bf16x8*)&sA[r][c];
            }
            #pragma unroll
            for (int j = 0; j < 4; j++) {
                int r = wc + j * 16 + (lane & 15);
                int c = ((kk * 4 + (lane >> 4)) ^ (r & 7)) << 3;
                bf0[j] = *(bf16x8*)&sB0[r][c];
                bf1[j] = *(bf16x8*)&sB1[r][c];
            }
            #pragma unroll
            for (int i = 0; i < 4; i++)
                #pragma unroll
                for (int j = 0; j < 4; j++) {
                    acc0[i][j] = __builtin_amdgcn_mfma_f32_16x16x32_bf16(
                        bf0[j], af[i], acc0[i][j], 0, 0, 0);
                    acc1[i][j] = __builtin_amdgcn_mfma_f32_16x16x32_bf16(
                        bf1[j], af[i], acc1[i][j], 0, 0, 0);
                }
        }
        __syncthreads();
    }
    short* outp;
    const float* bp2;
    int cb;
    if (n0 < N) { outp = Cl; bp2 = bias_l; cb = n0; }
    else        { outp = Cr; bp2 = bias_r; cb = n0 - N; }
    #pragma unroll
    for (int i = 0; i < 4; i++) {
        int rowg = m0 + wr + i * 16 + (lane & 15);
        #pragma unroll
        for (int j = 0; j < 4; j++) {
            int nl = cb + wc + j * 16 + (lane >> 4) * 4;
            float4 b0 = *(const float4*)(bp2 + nl);
            float4 b1 = *(const float4*)(bp2 + nl + 128);
            short o0[4], o1[4];
            o0[0] = f2bf(acc0[i][j][0] + b0.x); o0[1] = f2bf(acc0[i][j][1] + b0.y);
            o0[2] = f2bf(acc0[i][j][2] + b0.z); o0[3] = f2bf(acc0[i][j][3] + b0.w);
            o1[0] = f2bf(acc1[i][j][0] + b1.x); o1[1] = f2bf(acc1[i][j][1] + b1.y);
            o1[2] = f2bf(acc1[i][j][2] + b1.z); o1[3] = f2bf(acc1[i][j][3] + b1.w);
            *(bf16x4*)(outp + (size_t)rowg * N + nl)       = *(bf16x4*)o0;
            *(bf16x4*)(outp + (size_t)rowg * N + nl + 128) = *(bf16x4*)o1;
        }
    }
}

// ------------------------------------------------- GATv2 flash aggregation
// One wave per dst node; heads on lane-groups of G=64/H lanes; ILP-2 over
// edges (two gathers + two reduces in flight, merged online-softmax update).
template <int H, typename OT>
__global__ void k_gat_agg(const short* __restrict__ xl, const short* __restrict__ xr,
                          const float* __restrict__ att,
                          const int* __restrict__ rp, const int* __restrict__ csrc,
                          const float* __restrict__ bias,
                          const float* __restrict__ bng, const float* __restrict__ bnb,
                          const float* __restrict__ bnm, const float* __restrict__ bnv,
                          OT* __restrict__ out, int n) {
    constexpr int G = 64 / H;       // lanes per head group
    constexpr int CPL = 128 / G;    // channels per lane
    const int D = H * 128;
    int wid = (blockIdx.x * blockDim.x + threadIdx.x) >> 6;
    int lane = threadIdx.x & 63;
    if (wid >= n) return;
    const int i = wid;
    const int h = lane / G;
    const int ch0 = h * 128 + (lane % G) * CPL;

    float xrv[CPL], attv[CPL];
    {
        short raw[CPL];
        if constexpr (CPL == 8)
            *(bf16x8*)raw = *(const bf16x8*)(xr + (size_t)i * D + ch0);
        else
            *(bf16x4*)raw = *(const bf16x4*)(xr + (size_t)i * D + ch0);
        #pragma unroll
        for (int q = 0; q < CPL; q++) {
            xrv[q] = bf2f(raw[q]);
            attv[q] = att[ch0 + q];
        }
    }
    float m = -INFINITY, dnm = 0.f, acc[CPL] = {};

    int e0 = rp[i], e1 = rp[i + 1];
    int e = e0;
    for (; e + 1 < e1; e += 2) {
        int j0 = csrc[e], j1 = csrc[e + 1];
        float xlv0[CPL], xlv1[CPL];
        {
            short r0[CPL], r1[CPL];
            if constexpr (CPL == 8) {
                *(bf16x8*)r0 = *(const bf16x8*)(xl + (size_t)j0 * D + ch0);
                *(bf16x8*)r1 = *(const bf16x8*)(xl + (size_t)j1 * D + ch0);
            } else {
                *(bf16x4*)r0 = *(const bf16x4*)(xl + (size_t)j0 * D + ch0);
                *(bf16x4*)r1 = *(const bf16x4*)(xl + (size_t)j1 * D + ch0);
            }
            #pragma unroll
            for (int q = 0; q < CPL; q++) { xlv0[q] = bf2f(r0[q]); xlv1[q] = bf2f(r1[q]); }
        }
        float p0 = 0.f, p1 = 0.f;
        #pragma unroll
        for (int q = 0; q < CPL; q++) {
            float v0 = xlv0[q] + xrv[q];
            float v1 = xlv1[q] + xrv[q];
            v0 = fmaxf(v0, 0.2f * v0);
            v1 = fmaxf(v1, 0.2f * v1);
            p0 = fmaf(attv[q], v0, p0);
            p1 = fmaf(attv[q], v1, p1);
        }
        #pragma unroll
        for (int o = G / 2; o > 0; o >>= 1) {
            p0 += __shfl_xor(p0, o, 64);
            p1 += __shfl_xor(p1, o, 64);
        }
        float mn = fmaxf(m, fmaxf(p0, p1));
        float scale = __expf(m - mn);
        float w0 = __expf(p0 - mn);
        float w1 = __expf(p1 - mn);
        dnm = dnm * scale + w0 + w1;
        #pragma unroll
        for (int q = 0; q < CPL; q++)
            acc[q] = fmaf(w1, xlv1[q], fmaf(w0, xlv0[q], acc[q] * scale));
        m = mn;
    }
    if (e < e1) {
        int j = csrc[e];
        float xlv[CPL];
        {
            short raw[CPL];
            if constexpr (CPL == 8)
                *(bf16x8*)raw = *(const bf16x8*)(xl + (size_t)j * D + ch0);
            else
                *(bf16x4*)raw = *(const bf16x4*)(xl + (size_t)j * D + ch0);
            #pragma unroll
            for (int q = 0; q < CPL; q++) xlv[q] = bf2f(raw[q]);
        }
        float part = 0.f;
        #pragma unroll
        for (int q = 0; q < CPL; q++) {
            float v = xlv[q] + xrv[q];
            v = fmaxf(v, 0.2f * v);
            part = fmaf(attv[q], v, part);
        }
        #pragma unroll
        for (int o = G / 2; o > 0; o >>= 1) part += __shfl_xor(part, o, 64);
        float mn = fmaxf(m, part);
        float scale = __expf(m - mn);
        float p = __expf(part - mn);
        dnm = dnm * scale + p;
        #pragma unroll
        for (int q = 0; q < CPL; q++) acc[q] = fmaf(p, xlv[q], acc[q] * scale);
        m = mn;
    }

    float inv = 1.f / dnm;
    float res[CPL];
    #pragma unroll
    for (int q = 0; q < CPL; q++) {
        int ch = ch0 + q;
        float o = acc[q] * inv + bias[ch];
        float vv = (o - bnm[ch]) * rsqrtf(bnv[ch] + BN_EPS) * bng[ch] + bnb[ch];
        res[q] = fmaxf(vv, 0.f);
    }
    if constexpr (sizeof(OT) == 2) {
        short ov[CPL];
        #pragma unroll
        for (int q = 0; q < CPL; q++) ov[q] = f2bf(res[q]);
        if constexpr (CPL == 8)
            *(bf16x8*)(out + (size_t)i * D + ch0) = *(bf16x8*)ov;
        else
            *(bf16x4*)(out + (size_t)i * D + ch0) = *(bf16x4*)ov;
    } else {
        #pragma unroll
        for (int q = 0; q < CPL; q++) out[(size_t)i * D + ch0 + q] = res[q];
    }
}

// ---------------------------------------------------- per-node projection
// y[i] = (z_i . Wp_top[:,0], z_i . Wp_top[:,1], z_i . Wp_bot[:,0], z_i . Wp_bot[:,1])
// One wave per node; lane l covers ch = 4l..4l+3.
__global__ void k_zproj(const short* __restrict__ z, const float* __restrict__ Wp,
                        float* __restrict__ y, int n) {
    int wid = (blockIdx.x * blockDim.x + threadIdx.x) >> 6;
    int lane = threadIdx.x & 63;
    if (wid >= n) return;
    int ch = lane * 4;
    short raw[4];
    *(bf16x4*)raw = *(const bf16x4*)(z + (size_t)wid * 256 + ch);
    float a0 = 0.f, a1 = 0.f, a2 = 0.f, a3 = 0.f;
    #pragma unroll
    for (int q = 0; q < 4; q++) {
        float v = bf2f(raw[q]);
        a0 = fmaf(v, Wp[(ch + q) * 2 + 0], a0);
        a1 = fmaf(v, Wp[(ch + q) * 2 + 1], a1);
        a2 = fmaf(v, Wp[(256 + ch + q) * 2 + 0], a2);
        a3 = fmaf(v, Wp[(256 + ch + q) * 2 + 1], a3);
    }
    #pragma unroll
    for (int o = 32; o > 0; o >>= 1) {
        a0 += __shfl_xor(a0, o, 64);
        a1 += __shfl_xor(a1, o, 64);
        a2 += __shfl_xor(a2, o, 64);
        a3 += __shfl_xor(a3, o, 64);
    }
    if (lane == 0)
        *(float4*)(y + (size_t)wid * 4) = make_float4(a0, a1, a2, a3);
}

// ---------------------------------------------------------- prediction edge
// One THREAD per edge: out = y[s].top + y[d].bot + scalar tail.
__global__ void k_pred_edge(const float* __restrict__ y, const int* __restrict__ pe,
                            const float* __restrict__ pr, const float* __restrict__ pert,
                            const float* __restrict__ Wp, const float* __restrict__ bp,
                            float* __restrict__ out, int P) {
    int e = blockIdx.x * blockDim.x + threadIdx.x;
    if (e >= P) return;
    int s = pe[e], d = pe[P + e];
    float4 ys = *(const float4*)(y + (size_t)s * 4);
    float4 yd = *(const float4*)(y + (size_t)d * 4);
    float prs = pr[s], prd = pr[d], pp = pert[s] * pert[d];
    float o0 = ys.x + yd.z + prs * Wp[1024] + prd * Wp[1026] + pp * Wp[1028] + bp[0];
    float o1 = ys.y + yd.w + prs * Wp[1025] + prd * Wp[1027] + pp * Wp[1029] + bp[1];
    *(float2*)(out + (size_t)e * 2) = make_float2(o0, o1);
}

// ---------------------------------------------------------------------------

extern "C" void kernel_launch(void* const* d_in, const int* in_sizes, int n_in,
                              void* d_out, int out_size, void* d_ws, size_t ws_size,
                              hipStream_t stream) {
    const float* x    = (const float*)d_in[0];
    const int*   ei   = (const int*)d_in[1];
    const int*   pe   = (const int*)d_in[2];
    const float* pert = (const float*)d_in[3];
    const float* pr   = (const float*)d_in[4];
    const float* Wl1  = (const float*)d_in[5];
    const float* bl1  = (const float*)d_in[6];
    const float* Wr1  = (const float*)d_in[7];
    const float* br1  = (const float*)d_in[8];
    const float* att1 = (const float*)d_in[9];
    const float* bias1= (const float*)d_in[10];
    const float* bn1g = (const float*)d_in[11];
    const float* bn1b = (const float*)d_in[12];
    const float* bn1m = (const float*)d_in[13];
    const float* bn1v = (const float*)d_in[14];
    const float* Wl2  = (const float*)d_in[15];
    const float* bl2  = (const float*)d_in[16];
    const float* Wr2  = (const float*)d_in[17];
    const float* br2  = (const float*)d_in[18];
    const float* att2 = (const float*)d_in[19];
    const float* bias2= (const float*)d_in[20];
    const float* bn2g = (const float*)d_in[21];
    const float* bn2b = (const float*)d_in[22];
    const float* bn2m = (const float*)d_in[23];
    const float* bn2v = (const float*)d_in[24];
    const float* Wp   = (const float*)d_in[25];
    const float* bp   = (const float*)d_in[26];

    const int n  = in_sizes[3];          // 50000
    const int E  = in_sizes[1] / 2;      // 600000
    const int P  = in_sizes[2] / 2;      // 200000
    const int IN = in_sizes[0] / n;      // 128
    const int D1 = 512, D2 = 256;

    static short* xlb = nullptr;
    static short* xrb = nullptr;
    static short* h1b = nullptr;
    static short* xb  = nullptr;
    static short* zb  = nullptr;
    static float* yv  = nullptr;
    static short* wt  = nullptr;
    static int *rowptr = nullptr, *bsum = nullptr, *cursor = nullptr,
               *counts = nullptr, *csrc = nullptr;
    if (!xlb) {
        hipGetSymbolAddress((void**)&xlb,    HIP_SYMBOL(g_xlb));
        hipGetSymbolAddress((void**)&xrb,    HIP_SYMBOL(g_xrb));
        hipGetSymbolAddress((void**)&h1b,    HIP_SYMBOL(g_h1b));
        hipGetSymbolAddress((void**)&xb,     HIP_SYMBOL(g_xb));
        hipGetSymbolAddress((void**)&zb,     HIP_SYMBOL(g_zb));
        hipGetSymbolAddress((void**)&yv,     HIP_SYMBOL(g_y));
        hipGetSymbolAddress((void**)&wt,     HIP_SYMBOL(g_wt));
        hipGetSymbolAddress((void**)&rowptr, HIP_SYMBOL(g_rowptr));
        hipGetSymbolAddress((void**)&bsum,   HIP_SYMBOL(g_bsum));
        hipGetSymbolAddress((void**)&cursor, HIP_SYMBOL(g_cursor));
        hipGetSymbolAddress((void**)&counts, HIP_SYMBOL(g_counts));
        hipGetSymbolAddress((void**)&csrc,   HIP_SYMBOL(g_csrc));
    }

    short* xl1b = xlb;
    short* xr1b = xrb;
    short* xl2b = xlb;                              // reuse (lo half)
    short* xr2b = xlb + (size_t)M_PAD * D2;         // hi half (padded stride)
    short* WtL1 = wt;                               // stacked [1024][128]
    short* WtL2 = wt + 131072;                      // stacked [512][512]
    short* Wl1t = wt;
    short* Wr1t = wt + 65536;
    short* Wl2t = wt + 131072;
    short* Wr2t = wt + 262144;

    const int nb = (n + 255) / 256;

    // ---- CSR build
    k_init_counts<<<nb, 256, 0, stream>>>(counts, n);
    k_hist<<<(E + 255) / 256, 256, 0, stream>>>(ei, E, counts);
    k_scan1<<<nb, 256, 0, stream>>>(counts, n, rowptr, bsum);
    k_scan2<<<1, 256, 0, stream>>>(bsum, nb);
    k_scan3<<<nb, 256, 0, stream>>>(rowptr, bsum, n);
    k_fill<<<nb, 256, 0, stream>>>(rowptr, cursor, csrc, n);
    k_scatter<<<(E + 255) / 256, 256, 0, stream>>>(ei, E, cursor, csrc);

    // ---- bf16 conversions
    {
        int n4 = n * IN / 4;
        k_f32_to_bf16_v4<<<(n4 + 255) / 256, 256, 0, stream>>>(x, xb, n4);
        k_transpose_w<<<dim3(D1 / 32, IN / 32), dim3(32, 8), 0, stream>>>(Wl1, Wl1t, IN, D1);
        k_transpose_w<<<dim3(D1 / 32, IN / 32), dim3(32, 8), 0, stream>>>(Wr1, Wr1t, IN, D1);
        k_transpose_w<<<dim3(D2 / 32, D1 / 32), dim3(32, 8), 0, stream>>>(Wl2, Wl2t, D1, D2);
        k_transpose_w<<<dim3(D2 / 32, D1 / 32), dim3(32, 8), 0, stream>>>(Wr2, Wr2t, D1, D2);
    }

    const int mb = M_PAD / 128;   // 391

    // ---- layer 1 (fused dual GEMM: 2N=1024 cols -> 4 col-blocks)
    k_gemm_dual<<<dim3(2 * D1 / 256, mb), 256, 0, stream>>>(
        xb, WtL1, bl1, br1, xl1b, xr1b, D1, IN);
    k_gat_agg<4, short><<<(n + 3) / 4, 256, 0, stream>>>(xl1b, xr1b, att1, rowptr, csrc,
                                                  bias1, bn1g, bn1b, bn1m, bn1v, h1b, n);
    // ---- layer 2 (fused dual GEMM: 2N=512 cols -> 2 col-blocks)
    k_gemm_dual<<<dim3(2 * D2 / 256, mb), 256, 0, stream>>>(
        h1b, WtL2, bl2, br2, xl2b, xr2b, D2, D1);
    k_gat_agg<2, short><<<(n + 3) / 4, 256, 0, stream>>>(xl2b, xr2b, att2, rowptr, csrc,
                                                  bias2, bn2g, bn2b, bn2m, bn2v, zb, n);
    // ---- prediction head (projection factored through the gather)
    k_zproj<<<(n + 3) / 4, 256, 0, stream>>>(zb, Wp, yv, n);
    k_pred_edge<<<(P + 255) / 256, 256, 0, stream>>>(yv, pe, pr, pert, Wp, bp,
                                                     (float*)d_out, P);
}